// Round 1
// baseline (655.560 us; speedup 1.0000x reference)
//
#include <hip/hip_runtime.h>
#include <hip/hip_bf16.h>
#include <math.h>

// ---------------------------------------------------------------------------
// AttentionBlock: y[b,e] = sum_s w[b,s] * (x_bs @ V_s),
//   w = scores / ||scores||_2,  scores[b,s] = x_bs^T (Q_s K_s^T) x_bs
// Plan:
//   K0: memset scores = 0
//   K1: transpose V [16384,512] f32 -> Vt [512,16384] bf16
//   K2: G_s = K_s Q_s^T  (bf16, row-major [n][k]) so W[k][n] := G[n][k] = M[k][n]
//   K3: scores[b,s] += rowdot(x_bs, x_bs @ W)  (MFMA GEMM + fused epilogue)
//   K4: weights = scores / norm(scores)
//   K5: y = (w (.) x) @ Vf  (MFMA GEMM, weight applied at A-staging)
// ---------------------------------------------------------------------------

typedef __attribute__((ext_vector_type(8))) short s8v;   // 8 x bf16 bits
typedef __attribute__((ext_vector_type(4))) float f4v;   // 4 x f32

#define MFMA_BF16(a, b, c) __builtin_amdgcn_mfma_f32_16x16x32_bf16((a), (b), (c), 0, 0, 0)

constexpr int NB = 4096;     // batch
constexpr int NS = 32;       // segments
constexpr int ND = 512;      // d per segment
constexpr int NE = 512;      // e (output dim)
constexpr int SD = NS * ND;  // 16384

__device__ __forceinline__ short f2bf(float f) {
  union { float f; unsigned u; } v; v.f = f;
  unsigned r = v.u + 0x7fffu + ((v.u >> 16) & 1u);  // RNE
  return (short)(r >> 16);
}

__device__ __forceinline__ s8v cvt8(const float* p) {
  s8v r;
#pragma unroll
  for (int i = 0; i < 8; ++i) r[i] = f2bf(p[i]);
  return r;
}

// ---------------------------------------------------------------------------
// K1: V [SD, NE] f32  ->  Vt [NE, SD] bf16
// ---------------------------------------------------------------------------
__global__ __launch_bounds__(256) void k_transposeV(const float* __restrict__ V,
                                                    short* __restrict__ Vt) {
  __shared__ float t[64][65];
  int k0 = blockIdx.x * 64;
  int e0 = blockIdx.y * 64;
  int tid = threadIdx.x;
#pragma unroll
  for (int i = 0; i < 16; ++i) {
    int idx = tid + 256 * i;
    int r = idx >> 6, c = idx & 63;
    t[r][c] = V[(size_t)(k0 + r) * NE + e0 + c];
  }
  __syncthreads();
#pragma unroll
  for (int i = 0; i < 16; ++i) {
    int idx = tid + 256 * i;
    int e = idx >> 6, k = idx & 63;
    Vt[(size_t)(e0 + e) * SD + k0 + k] = f2bf(t[k][e]);
  }
}

// ---------------------------------------------------------------------------
// K2: G_s[i][j] = sum_e K_s[i,e] * Q_s[j,e]   (128x128 tile, BK=64)
// ---------------------------------------------------------------------------
__global__ __launch_bounds__(256) void k_gram(const float* __restrict__ Kw,
                                              const float* __restrict__ Qw,
                                              short* __restrict__ G) {
  int s = blockIdx.y;
  int tm = blockIdx.x >> 2, tn = blockIdx.x & 3;
  const float* A = Kw + (size_t)s * ND * NE + (size_t)tm * 128 * NE;
  const float* B = Qw + (size_t)s * ND * NE + (size_t)tn * 128 * NE;
  short* Gs = G + (size_t)s * ND * ND;

  __shared__ s8v lsA[128][9];
  __shared__ s8v lsB[128][9];

  int tid = threadIdx.x;
  int lane = tid & 63, wid = tid >> 6;
  int wr = wid >> 1, wc = wid & 1;
  int lhi = lane >> 4, llo = lane & 15;

  float ra[4][8], rb[4][8];
  f4v acc[4][4];
#pragma unroll
  for (int i = 0; i < 4; ++i)
#pragma unroll
    for (int j = 0; j < 4; ++j) acc[i][j] = (f4v)0.0f;

  auto loadRegs = [&](int k0) {
#pragma unroll
    for (int i = 0; i < 4; ++i) {
      int c = tid + 256 * i; int row = c >> 3, k8 = c & 7;
      const float* p = A + (size_t)row * NE + k0 + k8 * 8;
      *(f4v*)&ra[i][0] = *(const f4v*)p;
      *(f4v*)&ra[i][4] = *(const f4v*)(p + 4);
      const float* q = B + (size_t)row * NE + k0 + k8 * 8;
      *(f4v*)&rb[i][0] = *(const f4v*)q;
      *(f4v*)&rb[i][4] = *(const f4v*)(q + 4);
    }
  };
  auto writeLds = [&]() {
#pragma unroll
    for (int i = 0; i < 4; ++i) {
      int c = tid + 256 * i; int row = c >> 3, k8 = c & 7;
      lsA[row][k8] = cvt8(ra[i]);
      lsB[row][k8] = cvt8(rb[i]);
    }
  };

  loadRegs(0);
  writeLds();
  for (int kt = 0; kt < 8; ++kt) {
    __syncthreads();
    if (kt + 1 < 8) loadRegs((kt + 1) * 64);
#pragma unroll
    for (int kk = 0; kk < 2; ++kk) {
      s8v af[4], bq[4];
#pragma unroll
      for (int i = 0; i < 4; ++i) af[i] = lsA[wr * 64 + i * 16 + llo][kk * 4 + lhi];
#pragma unroll
      for (int j = 0; j < 4; ++j) bq[j] = lsB[wc * 64 + j * 16 + llo][kk * 4 + lhi];
#pragma unroll
      for (int i = 0; i < 4; ++i)
#pragma unroll
        for (int j = 0; j < 4; ++j) acc[i][j] = MFMA_BF16(af[i], bq[j], acc[i][j]);
    }
    __syncthreads();
    if (kt + 1 < 8) writeLds();
  }

#pragma unroll
  for (int i = 0; i < 4; ++i)
#pragma unroll
    for (int r = 0; r < 4; ++r) {
      int row = tm * 128 + wr * 64 + i * 16 + lhi * 4 + r;
#pragma unroll
      for (int j = 0; j < 4; ++j) {
        int col = tn * 128 + wc * 64 + j * 16 + llo;
        Gs[(size_t)row * ND + col] = f2bf(acc[i][j][r]);
      }
    }
}

// ---------------------------------------------------------------------------
// K3: T = X_s @ W  (W[k][n] = G[n][k]), scores[b,s] += sum_n X_s[b,n]*T[b,n]
// ---------------------------------------------------------------------------
__global__ __launch_bounds__(256) void k_scores(const float* __restrict__ x,
                                                const short* __restrict__ G,
                                                float* __restrict__ scores) {
  int s = blockIdx.y;
  int mt = blockIdx.x >> 2, nt = blockIdx.x & 3;
  int b0 = mt * 128, n0 = nt * 128;
  const float* A = x + (size_t)b0 * SD + s * ND;                 // LDA = SD
  const short* Bsrc = G + (size_t)s * ND * ND + (size_t)n0 * ND; // rows = n, LD = ND

  __shared__ s8v lsA[128][9];
  __shared__ s8v lsB[128][9];

  int tid = threadIdx.x;
  int lane = tid & 63, wid = tid >> 6;
  int wr = wid >> 1, wc = wid & 1;
  int lhi = lane >> 4, llo = lane & 15;

  float ra[4][8];
  s8v rbv[4];
  f4v acc[4][4];
#pragma unroll
  for (int i = 0; i < 4; ++i)
#pragma unroll
    for (int j = 0; j < 4; ++j) acc[i][j] = (f4v)0.0f;

  auto loadRegs = [&](int k0) {
#pragma unroll
    for (int i = 0; i < 4; ++i) {
      int c = tid + 256 * i; int row = c >> 3, k8 = c & 7;
      const float* p = A + (size_t)row * SD + k0 + k8 * 8;
      *(f4v*)&ra[i][0] = *(const f4v*)p;
      *(f4v*)&ra[i][4] = *(const f4v*)(p + 4);
      rbv[i] = *(const s8v*)(Bsrc + (size_t)row * ND + k0 + k8 * 8);
    }
  };
  auto writeLds = [&]() {
#pragma unroll
    for (int i = 0; i < 4; ++i) {
      int c = tid + 256 * i; int row = c >> 3, k8 = c & 7;
      lsA[row][k8] = cvt8(ra[i]);
      lsB[row][k8] = rbv[i];
    }
  };

  loadRegs(0);
  writeLds();
  for (int kt = 0; kt < 8; ++kt) {
    __syncthreads();
    if (kt + 1 < 8) loadRegs((kt + 1) * 64);
#pragma unroll
    for (int kk = 0; kk < 2; ++kk) {
      s8v af[4], bq[4];
#pragma unroll
      for (int i = 0; i < 4; ++i) af[i] = lsA[wr * 64 + i * 16 + llo][kk * 4 + lhi];
#pragma unroll
      for (int j = 0; j < 4; ++j) bq[j] = lsB[wc * 64 + j * 16 + llo][kk * 4 + lhi];
#pragma unroll
      for (int i = 0; i < 4; ++i)
#pragma unroll
        for (int j = 0; j < 4; ++j) acc[i][j] = MFMA_BF16(af[i], bq[j], acc[i][j]);
    }
    __syncthreads();
    if (kt + 1 < 8) writeLds();
  }

  // Fused epilogue: scores[b,s] += sum over this block's n-range of x*T
#pragma unroll
  for (int i = 0; i < 4; ++i)
#pragma unroll
    for (int r = 0; r < 4; ++r) {
      int rowl = wr * 64 + i * 16 + lhi * 4 + r;
      int b = b0 + rowl;
      const float* xr = x + (size_t)b * SD + s * ND + n0 + wc * 64;
      float v = 0.f;
#pragma unroll
      for (int j = 0; j < 4; ++j) v += xr[j * 16 + llo] * acc[i][j][r];
      v += __shfl_xor(v, 1);
      v += __shfl_xor(v, 2);
      v += __shfl_xor(v, 4);
      v += __shfl_xor(v, 8);
      if (llo == 0) atomicAdd(&scores[b * NS + s], v);
    }
}

// ---------------------------------------------------------------------------
// K4: weights = scores / ||scores||_2 (per row of 32)
// ---------------------------------------------------------------------------
__global__ __launch_bounds__(256) void k_weights(const float* __restrict__ scores,
                                                 float* __restrict__ w) {
  int b = blockIdx.x * 256 + threadIdx.x;
  float sq = 0.f, sc[NS];
#pragma unroll
  for (int s = 0; s < NS; ++s) { sc[s] = scores[b * NS + s]; sq += sc[s] * sc[s]; }
  float inv = 1.0f / sqrtf(sq);
#pragma unroll
  for (int s = 0; s < NS; ++s) w[b * NS + s] = sc[s] * inv;
}

// ---------------------------------------------------------------------------
// K5: y = (w (.) x) @ Vf    tile 128x64, BK=64, K = 16384
// ---------------------------------------------------------------------------
__global__ __launch_bounds__(256) void k_out(const float* __restrict__ x,
                                             const float* __restrict__ wts,
                                             const short* __restrict__ Vt,
                                             float* __restrict__ y) {
  int mt = blockIdx.x >> 3, nt = blockIdx.x & 7;  // n fastest for L3 reuse of x
  int b0 = mt * 128, n0 = nt * 64;
  const float* A = x + (size_t)b0 * SD;
  const short* Bsrc = Vt + (size_t)n0 * SD;  // rows = e, LD = SD

  __shared__ s8v lsA[128][9];
  __shared__ s8v lsB[64][9];

  int tid = threadIdx.x;
  int lane = tid & 63, wid = tid >> 6;
  int wr = wid >> 1, wc = wid & 1;
  int lhi = lane >> 4, llo = lane & 15;

  float ra[4][8], rs[4];
  s8v rbv[2];
  f4v acc[4][2];
#pragma unroll
  for (int i = 0; i < 4; ++i)
#pragma unroll
    for (int j = 0; j < 2; ++j) acc[i][j] = (f4v)0.0f;

  auto loadRegs = [&](int k0) {
#pragma unroll
    for (int i = 0; i < 4; ++i) {
      int c = tid + 256 * i; int row = c >> 3, k8 = c & 7;
      const float* p = A + (size_t)row * SD + k0 + k8 * 8;
      *(f4v*)&ra[i][0] = *(const f4v*)p;
      *(f4v*)&ra[i][4] = *(const f4v*)(p + 4);
      rs[i] = wts[(b0 + row) * NS + ((k0 + k8 * 8) >> 9)];
    }
#pragma unroll
    for (int i = 0; i < 2; ++i) {
      int c = tid + 256 * i; int row = c >> 3, k8 = c & 7;
      rbv[i] = *(const s8v*)(Bsrc + (size_t)row * SD + k0 + k8 * 8);
    }
  };
  auto writeLds = [&]() {
#pragma unroll
    for (int i = 0; i < 4; ++i) {
      int c = tid + 256 * i; int row = c >> 3, k8 = c & 7;
      float t[8];
#pragma unroll
      for (int u = 0; u < 8; ++u) t[u] = ra[i][u] * rs[i];
      lsA[row][k8] = cvt8(t);
    }
#pragma unroll
    for (int i = 0; i < 2; ++i) {
      int c = tid + 256 * i; int row = c >> 3, k8 = c & 7;
      lsB[row][k8] = rbv[i];
    }
  };

  loadRegs(0);
  writeLds();
  for (int kt = 0; kt < 256; ++kt) {
    __syncthreads();
    if (kt + 1 < 256) loadRegs((kt + 1) * 64);
#pragma unroll
    for (int kk = 0; kk < 2; ++kk) {
      s8v af[4], bq[2];
#pragma unroll
      for (int i = 0; i < 4; ++i) af[i] = lsA[wr * 64 + i * 16 + llo][kk * 4 + lhi];
#pragma unroll
      for (int j = 0; j < 2; ++j) bq[j] = lsB[wc * 32 + j * 16 + llo][kk * 4 + lhi];
#pragma unroll
      for (int i = 0; i < 4; ++i)
#pragma unroll
        for (int j = 0; j < 2; ++j) acc[i][j] = MFMA_BF16(af[i], bq[j], acc[i][j]);
    }
    __syncthreads();
    if (kt + 1 < 256) writeLds();
  }

#pragma unroll
  for (int i = 0; i < 4; ++i)
#pragma unroll
    for (int r = 0; r < 4; ++r) {
      int row = b0 + wr * 64 + i * 16 + lhi * 4 + r;
#pragma unroll
      for (int j = 0; j < 2; ++j) {
        int col = n0 + wc * 32 + j * 16 + llo;
        y[(size_t)row * NE + col] = acc[i][j][r];
      }
    }
}

// ---------------------------------------------------------------------------
extern "C" void kernel_launch(void* const* d_in, const int* in_sizes, int n_in,
                              void* d_out, int out_size, void* d_ws, size_t ws_size,
                              hipStream_t stream) {
  const float* x  = (const float*)d_in[0];
  const float* Qw = (const float*)d_in[1];
  const float* Kw = (const float*)d_in[2];
  const float* Vw = (const float*)d_in[3];
  float* y = (float*)d_out;

  char* ws = (char*)d_ws;
  short* G      = (short*)ws;                                   // 16 MiB
  short* Vt     = (short*)(ws + (size_t)16 * 1024 * 1024);      // 16 MiB
  float* scores = (float*)(ws + (size_t)32 * 1024 * 1024);      // 512 KiB
  float* wts    = (float*)(ws + (size_t)32 * 1024 * 1024 + 512 * 1024);

  hipMemsetAsync(scores, 0, (size_t)NB * NS * sizeof(float), stream);
  k_transposeV<<<dim3(SD / 64, NE / 64), 256, 0, stream>>>(Vw, Vt);
  k_gram<<<dim3(16, NS), 256, 0, stream>>>(Kw, Qw, G);
  k_scores<<<dim3(128, NS), 256, 0, stream>>>(x, G, scores);
  k_weights<<<NB / 256, 256, 0, stream>>>(scores, wts);
  k_out<<<256, 256, 0, stream>>>(x, wts, Vt, y);
}

// Round 2
// 602.513 us; speedup vs baseline: 1.0880x; 1.0880x over previous
//
#include <hip/hip_runtime.h>
#include <hip/hip_bf16.h>
#include <math.h>

// ---------------------------------------------------------------------------
// AttentionBlock: y[b,e] = sum_s w[b,s] * (x_bs @ V_s),
//   w = scores / ||scores||_2,  scores[b,s] = x_bs^T (Q_s K_s^T) x_bs
// Round 2: pre-cast x->bf16 once; both big GEMMs use global_load_lds (m97
// structure, pure-bf16 LDS tiles); k_out split by segment-group (4-way) for
// occupancy, weight applied to MFMA output per segment, atomicAdd into y.
// ---------------------------------------------------------------------------

typedef __attribute__((ext_vector_type(8))) short s8v;   // 8 x bf16 bits
typedef __attribute__((ext_vector_type(4))) float f4v;   // 4 x f32

#define MFMA_BF16(a, b, c) __builtin_amdgcn_mfma_f32_16x16x32_bf16((a), (b), (c), 0, 0, 0)

constexpr int NB = 4096;     // batch
constexpr int NS = 32;       // segments
constexpr int ND = 512;      // d per segment
constexpr int NE = 512;      // e (output dim)
constexpr int SD = NS * ND;  // 16384

__device__ __forceinline__ short f2bf(float f) {
  union { float f; unsigned u; } v; v.f = f;
  unsigned r = v.u + 0x7fffu + ((v.u >> 16) & 1u);  // RNE
  return (short)(r >> 16);
}
__device__ __forceinline__ float bf2f(short h) {
  union { unsigned u; float f; } v; v.u = ((unsigned)(unsigned short)h) << 16;
  return v.f;
}
__device__ __forceinline__ s8v cvt8(const float* p) {
  s8v r;
#pragma unroll
  for (int i = 0; i < 8; ++i) r[i] = f2bf(p[i]);
  return r;
}

// global -> LDS direct (16B per lane). LDS base must be wave-uniform.
__device__ __forceinline__ void gload16(const void* g, void* l) {
  __builtin_amdgcn_global_load_lds(
      (const __attribute__((address_space(1))) unsigned int*)g,
      (__attribute__((address_space(3))) unsigned int*)l, 16, 0, 0);
}

// ---------------------------------------------------------------------------
// K_cast: x f32 -> xb bf16 (grid-stride, 8 elems/thread/iter)
// ---------------------------------------------------------------------------
__global__ __launch_bounds__(256) void k_castx(const float* __restrict__ x,
                                               short* __restrict__ xb) {
  size_t i = ((size_t)blockIdx.x * 256 + threadIdx.x) * 8;
  size_t stride = (size_t)gridDim.x * 256 * 8;
  size_t total = (size_t)NB * SD;
  for (; i < total; i += stride) {
    f4v a = *(const f4v*)(x + i);
    f4v b = *(const f4v*)(x + i + 4);
    s8v o;
#pragma unroll
    for (int u = 0; u < 4; ++u) { o[u] = f2bf(a[u]); o[4 + u] = f2bf(b[u]); }
    *(s8v*)(xb + i) = o;
  }
}

// ---------------------------------------------------------------------------
// K1: V [SD, NE] f32  ->  Vt [NE, SD] bf16
// ---------------------------------------------------------------------------
__global__ __launch_bounds__(256) void k_transposeV(const float* __restrict__ V,
                                                    short* __restrict__ Vt) {
  __shared__ float t[64][65];
  int k0 = blockIdx.x * 64;
  int e0 = blockIdx.y * 64;
  int tid = threadIdx.x;
#pragma unroll
  for (int i = 0; i < 16; ++i) {
    int idx = tid + 256 * i;
    int r = idx >> 6, c = idx & 63;
    t[r][c] = V[(size_t)(k0 + r) * NE + e0 + c];
  }
  __syncthreads();
#pragma unroll
  for (int i = 0; i < 16; ++i) {
    int idx = tid + 256 * i;
    int e = idx >> 6, k = idx & 63;
    Vt[(size_t)(e0 + e) * SD + k0 + k] = f2bf(t[k][e]);
  }
}

// ---------------------------------------------------------------------------
// K2: G_s[i][j] = sum_e K_s[i,e] * Q_s[j,e]   (128x128 tile, BK=64, f32 in)
// ---------------------------------------------------------------------------
__global__ __launch_bounds__(256) void k_gram(const float* __restrict__ Kw,
                                              const float* __restrict__ Qw,
                                              short* __restrict__ G) {
  int s = blockIdx.y;
  int tm = blockIdx.x >> 2, tn = blockIdx.x & 3;
  const float* A = Kw + (size_t)s * ND * NE + (size_t)tm * 128 * NE;
  const float* B = Qw + (size_t)s * ND * NE + (size_t)tn * 128 * NE;
  short* Gs = G + (size_t)s * ND * ND;

  __shared__ s8v lsA[128][9];
  __shared__ s8v lsB[128][9];

  int tid = threadIdx.x;
  int lane = tid & 63, wid = tid >> 6;
  int wr = wid >> 1, wc = wid & 1;
  int lhi = lane >> 4, llo = lane & 15;

  float ra[4][8], rb[4][8];
  f4v acc[4][4];
#pragma unroll
  for (int i = 0; i < 4; ++i)
#pragma unroll
    for (int j = 0; j < 4; ++j) acc[i][j] = (f4v)0.0f;

  auto loadRegs = [&](int k0) {
#pragma unroll
    for (int i = 0; i < 4; ++i) {
      int c = tid + 256 * i; int row = c >> 3, k8 = c & 7;
      const float* p = A + (size_t)row * NE + k0 + k8 * 8;
      *(f4v*)&ra[i][0] = *(const f4v*)p;
      *(f4v*)&ra[i][4] = *(const f4v*)(p + 4);
      const float* q = B + (size_t)row * NE + k0 + k8 * 8;
      *(f4v*)&rb[i][0] = *(const f4v*)q;
      *(f4v*)&rb[i][4] = *(const f4v*)(q + 4);
    }
  };
  auto writeLds = [&]() {
#pragma unroll
    for (int i = 0; i < 4; ++i) {
      int c = tid + 256 * i; int row = c >> 3, k8 = c & 7;
      lsA[row][k8] = cvt8(ra[i]);
      lsB[row][k8] = cvt8(rb[i]);
    }
  };

  loadRegs(0);
  writeLds();
  for (int kt = 0; kt < 8; ++kt) {
    __syncthreads();
    if (kt + 1 < 8) loadRegs((kt + 1) * 64);
#pragma unroll
    for (int kk = 0; kk < 2; ++kk) {
      s8v af[4], bq[4];
#pragma unroll
      for (int i = 0; i < 4; ++i) af[i] = lsA[wr * 64 + i * 16 + llo][kk * 4 + lhi];
#pragma unroll
      for (int j = 0; j < 4; ++j) bq[j] = lsB[wc * 64 + j * 16 + llo][kk * 4 + lhi];
#pragma unroll
      for (int i = 0; i < 4; ++i)
#pragma unroll
        for (int j = 0; j < 4; ++j) acc[i][j] = MFMA_BF16(af[i], bq[j], acc[i][j]);
    }
    __syncthreads();
    if (kt + 1 < 8) writeLds();
  }

#pragma unroll
  for (int i = 0; i < 4; ++i)
#pragma unroll
    for (int r = 0; r < 4; ++r) {
      int row = tm * 128 + wr * 64 + i * 16 + lhi * 4 + r;
#pragma unroll
      for (int j = 0; j < 4; ++j) {
        int col = tn * 128 + wc * 64 + j * 16 + llo;
        Gs[(size_t)row * ND + col] = f2bf(acc[i][j][r]);
      }
    }
}

// ---------------------------------------------------------------------------
// K3: T = Xb_s @ W, scores[b,s] += sum_n Xb_s[b,n]*T[b,n]
//     128x128 tile, BK=64, pure bf16, global_load_lds staging
// ---------------------------------------------------------------------------
__global__ __launch_bounds__(256) void k_scores(const short* __restrict__ xb,
                                                const short* __restrict__ G,
                                                float* __restrict__ scores) {
  int s = blockIdx.y;
  int mt = blockIdx.x >> 2, nt = blockIdx.x & 3;
  int b0 = mt * 128, n0 = nt * 128;
  const short* Asrc = xb + (size_t)b0 * SD + s * ND;              // LD = SD
  const short* Bsrc = G + (size_t)s * ND * ND + (size_t)n0 * ND;  // LD = ND

  __shared__ __align__(16) short lsA[128 * 64];
  __shared__ __align__(16) short lsB[128 * 64];

  int tid = threadIdx.x;
  int lane = tid & 63, wid = tid >> 6;
  int wr = wid >> 1, wc = wid & 1;
  int lhi = lane >> 4, llo = lane & 15;
  int lrow = lane >> 3, lcol = (lane & 7) * 8;

  f4v acc[4][4];
#pragma unroll
  for (int i = 0; i < 4; ++i)
#pragma unroll
    for (int j = 0; j < 4; ++j) acc[i][j] = (f4v)0.0f;

  for (int kt = 0; kt < 8; ++kt) {
    int k0 = kt * 64;
#pragma unroll
    for (int c = 0; c < 4; ++c) {
      int chunk = wid * 4 + c;                 // 0..15, 8 rows each
      int row = chunk * 8 + lrow;
      gload16(Asrc + (size_t)row * SD + k0 + lcol, (char*)lsA + chunk * 1024);
      gload16(Bsrc + (size_t)row * ND + k0 + lcol, (char*)lsB + chunk * 1024);
    }
    __syncthreads();  // drains vmcnt -> tile resident
    const s8v* fA = (const s8v*)lsA;
    const s8v* fB = (const s8v*)lsB;
#pragma unroll
    for (int kk = 0; kk < 2; ++kk) {
      s8v af[4], bq[4];
#pragma unroll
      for (int i = 0; i < 4; ++i) af[i] = fA[(wr * 64 + i * 16 + llo) * 8 + kk * 4 + lhi];
#pragma unroll
      for (int j = 0; j < 4; ++j) bq[j] = fB[(wc * 64 + j * 16 + llo) * 8 + kk * 4 + lhi];
#pragma unroll
      for (int i = 0; i < 4; ++i)
#pragma unroll
        for (int j = 0; j < 4; ++j) acc[i][j] = MFMA_BF16(af[i], bq[j], acc[i][j]);
    }
    __syncthreads();
  }

  // Fused epilogue: scores[b,s] += sum over this block's n-range of x*T
#pragma unroll
  for (int i = 0; i < 4; ++i)
#pragma unroll
    for (int r = 0; r < 4; ++r) {
      int rowl = wr * 64 + i * 16 + lhi * 4 + r;
      int b = b0 + rowl;
      const short* xr = xb + (size_t)b * SD + s * ND + n0 + wc * 64;
      float v = 0.f;
#pragma unroll
      for (int j = 0; j < 4; ++j) v += bf2f(xr[j * 16 + llo]) * acc[i][j][r];
      v += __shfl_xor(v, 1);
      v += __shfl_xor(v, 2);
      v += __shfl_xor(v, 4);
      v += __shfl_xor(v, 8);
      if (llo == 0) atomicAdd(&scores[b * NS + s], v);
    }
}

// ---------------------------------------------------------------------------
// K4: weights = scores / ||scores||_2 (per row of 32)
// ---------------------------------------------------------------------------
__global__ __launch_bounds__(256) void k_weights(const float* __restrict__ scores,
                                                 float* __restrict__ w) {
  int b = blockIdx.x * 256 + threadIdx.x;
  float sq = 0.f, sc[NS];
#pragma unroll
  for (int s = 0; s < NS; ++s) { sc[s] = scores[b * NS + s]; sq += sc[s] * sc[s]; }
  float inv = 1.0f / sqrtf(sq);
#pragma unroll
  for (int s = 0; s < NS; ++s) w[b * NS + s] = sc[s] * inv;
}

// ---------------------------------------------------------------------------
// K5: y += sum_{s in group} w[b,s] * (xb_s @ V_s)
//     tile 128x64, BK=64, 4 segment-groups (split-K), weight on MFMA output
// ---------------------------------------------------------------------------
__global__ __launch_bounds__(256) void k_out(const short* __restrict__ xb,
                                             const float* __restrict__ wts,
                                             const short* __restrict__ Vt,
                                             float* __restrict__ y) {
  int mt = blockIdx.x >> 3, nt = blockIdx.x & 7;
  int kg = blockIdx.y;                         // segment group: 8 segments
  int b0 = mt * 128, n0 = nt * 64;
  const short* Asrc = xb + (size_t)b0 * SD + kg * 4096;  // LD = SD
  const short* Bsrc = Vt + (size_t)n0 * SD + kg * 4096;  // LD = SD

  __shared__ __align__(16) short lsA[128 * 64];
  __shared__ __align__(16) short lsB[64 * 64];
  __shared__ float wl[128 * 8];

  int tid = threadIdx.x;
  int lane = tid & 63, wid = tid >> 6;
  int wr = wid >> 1, wc = wid & 1;
  int lhi = lane >> 4, llo = lane & 15;
  int lrow = lane >> 3, lcol = (lane & 7) * 8;

  {  // stage weights for this row-block / segment-group: wl[row][sg]
    int f = tid * 4;
    int row = f >> 3, sg = f & 7;
    *(f4v*)&wl[f] = *(const f4v*)&wts[(size_t)(b0 + row) * NS + kg * 8 + sg];
  }

  f4v acc[4][2], yac[4][2];
#pragma unroll
  for (int i = 0; i < 4; ++i)
#pragma unroll
    for (int j = 0; j < 2; ++j) { acc[i][j] = (f4v)0.0f; yac[i][j] = (f4v)0.0f; }

  for (int s = 0; s < 8; ++s) {
#pragma unroll 1
    for (int kt = 0; kt < 8; ++kt) {
      int k0 = s * 512 + kt * 64;
#pragma unroll
      for (int c = 0; c < 4; ++c) {
        int chunk = wid * 4 + c;
        gload16(Asrc + (size_t)(chunk * 8 + lrow) * SD + k0 + lcol, (char*)lsA + chunk * 1024);
      }
#pragma unroll
      for (int c = 0; c < 2; ++c) {
        int chunk = wid * 2 + c;               // 0..7, rows 0..63
        gload16(Bsrc + (size_t)(chunk * 8 + lrow) * SD + k0 + lcol, (char*)lsB + chunk * 1024);
      }
      __syncthreads();
      const s8v* fA = (const s8v*)lsA;
      const s8v* fB = (const s8v*)lsB;
#pragma unroll
      for (int kk = 0; kk < 2; ++kk) {
        s8v af[4], bq[2];
#pragma unroll
        for (int i = 0; i < 4; ++i) af[i] = fA[(wr * 64 + i * 16 + llo) * 8 + kk * 4 + lhi];
#pragma unroll
        for (int j = 0; j < 2; ++j) bq[j] = fB[(wc * 32 + j * 16 + llo) * 8 + kk * 4 + lhi];
#pragma unroll
        for (int i = 0; i < 4; ++i)
#pragma unroll
          for (int j = 0; j < 2; ++j) acc[i][j] = MFMA_BF16(af[i], bq[j], acc[i][j]);
      }
      __syncthreads();
    }
    // fold this segment into y-accumulator with its weight
#pragma unroll
    for (int i = 0; i < 4; ++i)
#pragma unroll
      for (int r = 0; r < 4; ++r) {
        float wv = wl[(wr * 64 + i * 16 + lhi * 4 + r) * 8 + s];
#pragma unroll
        for (int j = 0; j < 2; ++j) yac[i][j][r] += wv * acc[i][j][r];
      }
#pragma unroll
    for (int i = 0; i < 4; ++i)
#pragma unroll
      for (int j = 0; j < 2; ++j) acc[i][j] = (f4v)0.0f;
  }

#pragma unroll
  for (int i = 0; i < 4; ++i)
#pragma unroll
    for (int r = 0; r < 4; ++r) {
      int row = b0 + wr * 64 + i * 16 + lhi * 4 + r;
#pragma unroll
      for (int j = 0; j < 2; ++j) {
        int col = n0 + wc * 32 + j * 16 + llo;
        atomicAdd(&y[(size_t)row * NE + col], yac[i][j][r]);
      }
    }
}

// ---------------------------------------------------------------------------
extern "C" void kernel_launch(void* const* d_in, const int* in_sizes, int n_in,
                              void* d_out, int out_size, void* d_ws, size_t ws_size,
                              hipStream_t stream) {
  const float* x  = (const float*)d_in[0];
  const float* Qw = (const float*)d_in[1];
  const float* Kw = (const float*)d_in[2];
  const float* Vw = (const float*)d_in[3];
  float* y = (float*)d_out;

  char* ws = (char*)d_ws;
  short* xb     = (short*)ws;                                    // 128 MiB
  short* G      = (short*)(ws + (size_t)128 * 1024 * 1024);      // 16 MiB
  short* Vt     = (short*)(ws + (size_t)144 * 1024 * 1024);      // 16 MiB
  float* scores = (float*)(ws + (size_t)160 * 1024 * 1024);      // 512 KiB
  float* wts    = (float*)(ws + (size_t)160 * 1024 * 1024 + 512 * 1024);

  hipMemsetAsync(scores, 0, (size_t)NB * NS * sizeof(float), stream);
  hipMemsetAsync(y, 0, (size_t)NB * NE * sizeof(float), stream);
  k_castx<<<2048, 256, 0, stream>>>(x, xb);
  k_transposeV<<<dim3(SD / 64, NE / 64), 256, 0, stream>>>(Vw, Vt);
  k_gram<<<dim3(16, NS), 256, 0, stream>>>(Kw, Qw, G);
  k_scores<<<dim3(128, NS), 256, 0, stream>>>(xb, G, scores);
  k_weights<<<NB / 256, 256, 0, stream>>>(scores, wts);
  k_out<<<dim3(256, 4), 256, 0, stream>>>(xb, wts, Vt, y);
}

// Round 3
// 428.078 us; speedup vs baseline: 1.5314x; 1.4075x over previous
//
#include <hip/hip_runtime.h>
#include <hip/hip_bf16.h>
#include <math.h>

// ---------------------------------------------------------------------------
// AttentionBlock: y[b,e] = sum_s w[b,s] * (x_bs @ V_s),
//   w = scores / ||scores||_2,  scores[b,s] = x_bs^T (Q_s K_s^T) x_bs
// Round 3: occupancy-first m97-structure GEMMs.
//   castx: x f32 -> xb bf16
//   transposeV: V -> Vt[e][k] bf16
//   gram: G_s = K_s Q_s^T (bf16)
//   scores: 128x128x512-per-segment GEMM + fused row-dot epilogue (atomic)
//   weights: L2 normalize
//   scale: xb *= w[b,s] in place  -> xw
//   out: pure GEMM y = xw @ Vt^T, 128x128 tile, split-K 8, atomicAdd
// ---------------------------------------------------------------------------

typedef __attribute__((ext_vector_type(8))) short s8v;   // 8 x bf16 bits
typedef __attribute__((ext_vector_type(4))) float f4v;   // 4 x f32

#define MFMA_BF16(a, b, c) __builtin_amdgcn_mfma_f32_16x16x32_bf16((a), (b), (c), 0, 0, 0)

constexpr int NB = 4096;     // batch
constexpr int NS = 32;       // segments
constexpr int ND = 512;      // d per segment
constexpr int NE = 512;      // e (output dim)
constexpr int SD = NS * ND;  // 16384

__device__ __forceinline__ short f2bf(float f) {
  union { float f; unsigned u; } v; v.f = f;
  unsigned r = v.u + 0x7fffu + ((v.u >> 16) & 1u);  // RNE
  return (short)(r >> 16);
}
__device__ __forceinline__ float bf2f(short h) {
  union { unsigned u; float f; } v; v.u = ((unsigned)(unsigned short)h) << 16;
  return v.f;
}
__device__ __forceinline__ s8v cvt8(const float* p) {
  s8v r;
#pragma unroll
  for (int i = 0; i < 8; ++i) r[i] = f2bf(p[i]);
  return r;
}

// global -> LDS direct (16B per lane). LDS base must be wave-uniform.
__device__ __forceinline__ void gload16(const void* g, void* l) {
  __builtin_amdgcn_global_load_lds(
      (const __attribute__((address_space(1))) unsigned int*)g,
      (__attribute__((address_space(3))) unsigned int*)l, 16, 0, 0);
}

// ---------------------------------------------------------------------------
// K_cast: x f32 -> xb bf16 (grid-stride, 8 elems/thread/iter)
// ---------------------------------------------------------------------------
__global__ __launch_bounds__(256) void k_castx(const float* __restrict__ x,
                                               short* __restrict__ xb) {
  size_t i = ((size_t)blockIdx.x * 256 + threadIdx.x) * 8;
  size_t stride = (size_t)gridDim.x * 256 * 8;
  size_t total = (size_t)NB * SD;
  for (; i < total; i += stride) {
    f4v a = *(const f4v*)(x + i);
    f4v b = *(const f4v*)(x + i + 4);
    s8v o;
#pragma unroll
    for (int u = 0; u < 4; ++u) { o[u] = f2bf(a[u]); o[4 + u] = f2bf(b[u]); }
    *(s8v*)(xb + i) = o;
  }
}

// ---------------------------------------------------------------------------
// K1: V [SD, NE] f32  ->  Vt [NE, SD] bf16
// ---------------------------------------------------------------------------
__global__ __launch_bounds__(256) void k_transposeV(const float* __restrict__ V,
                                                    short* __restrict__ Vt) {
  __shared__ float t[64][65];
  int k0 = blockIdx.x * 64;
  int e0 = blockIdx.y * 64;
  int tid = threadIdx.x;
#pragma unroll
  for (int i = 0; i < 16; ++i) {
    int idx = tid + 256 * i;
    int r = idx >> 6, c = idx & 63;
    t[r][c] = V[(size_t)(k0 + r) * NE + e0 + c];
  }
  __syncthreads();
#pragma unroll
  for (int i = 0; i < 16; ++i) {
    int idx = tid + 256 * i;
    int e = idx >> 6, k = idx & 63;
    Vt[(size_t)(e0 + e) * SD + k0 + k] = f2bf(t[k][e]);
  }
}

// ---------------------------------------------------------------------------
// K2: G_s[i][j] = sum_e K_s[i,e] * Q_s[j,e]   (128x128 tile, BK=64, f32 in)
// ---------------------------------------------------------------------------
__global__ __launch_bounds__(256) void k_gram(const float* __restrict__ Kw,
                                              const float* __restrict__ Qw,
                                              short* __restrict__ G) {
  int s = blockIdx.y;
  int tm = blockIdx.x >> 2, tn = blockIdx.x & 3;
  const float* A = Kw + (size_t)s * ND * NE + (size_t)tm * 128 * NE;
  const float* B = Qw + (size_t)s * ND * NE + (size_t)tn * 128 * NE;
  short* Gs = G + (size_t)s * ND * ND;

  __shared__ s8v lsA[128][9];
  __shared__ s8v lsB[128][9];

  int tid = threadIdx.x;
  int lane = tid & 63, wid = tid >> 6;
  int wr = wid >> 1, wc = wid & 1;
  int lhi = lane >> 4, llo = lane & 15;

  float ra[4][8], rb[4][8];
  f4v acc[4][4];
#pragma unroll
  for (int i = 0; i < 4; ++i)
#pragma unroll
    for (int j = 0; j < 4; ++j) acc[i][j] = (f4v)0.0f;

  auto loadRegs = [&](int k0) {
#pragma unroll
    for (int i = 0; i < 4; ++i) {
      int c = tid + 256 * i; int row = c >> 3, k8 = c & 7;
      const float* p = A + (size_t)row * NE + k0 + k8 * 8;
      *(f4v*)&ra[i][0] = *(const f4v*)p;
      *(f4v*)&ra[i][4] = *(const f4v*)(p + 4);
      const float* q = B + (size_t)row * NE + k0 + k8 * 8;
      *(f4v*)&rb[i][0] = *(const f4v*)q;
      *(f4v*)&rb[i][4] = *(const f4v*)(q + 4);
    }
  };
  auto writeLds = [&]() {
#pragma unroll
    for (int i = 0; i < 4; ++i) {
      int c = tid + 256 * i; int row = c >> 3, k8 = c & 7;
      lsA[row][k8] = cvt8(ra[i]);
      lsB[row][k8] = cvt8(rb[i]);
    }
  };

  loadRegs(0);
  writeLds();
  for (int kt = 0; kt < 8; ++kt) {
    __syncthreads();
    if (kt + 1 < 8) loadRegs((kt + 1) * 64);
#pragma unroll
    for (int kk = 0; kk < 2; ++kk) {
      s8v af[4], bq[4];
#pragma unroll
      for (int i = 0; i < 4; ++i) af[i] = lsA[wr * 64 + i * 16 + llo][kk * 4 + lhi];
#pragma unroll
      for (int j = 0; j < 4; ++j) bq[j] = lsB[wc * 64 + j * 16 + llo][kk * 4 + lhi];
#pragma unroll
      for (int i = 0; i < 4; ++i)
#pragma unroll
        for (int j = 0; j < 4; ++j) acc[i][j] = MFMA_BF16(af[i], bq[j], acc[i][j]);
    }
    __syncthreads();
    if (kt + 1 < 8) writeLds();
  }

#pragma unroll
  for (int i = 0; i < 4; ++i)
#pragma unroll
    for (int r = 0; r < 4; ++r) {
      int row = tm * 128 + wr * 64 + i * 16 + lhi * 4 + r;
#pragma unroll
      for (int j = 0; j < 4; ++j) {
        int col = tn * 128 + wc * 64 + j * 16 + llo;
        Gs[(size_t)row * ND + col] = f2bf(acc[i][j][r]);
      }
    }
}

// ---------------------------------------------------------------------------
// K3: T = Xb_s @ W, scores[b,s] += sum_n Xb_s[b,n]*T[b,n]
//     128x128 tile, BK=64, pure bf16, global_load_lds, single-buffer
// ---------------------------------------------------------------------------
__global__ __launch_bounds__(256, 3) void k_scores(const short* __restrict__ xb,
                                                   const short* __restrict__ G,
                                                   float* __restrict__ scores) {
  // grid 4096 = 32 s x 32 mt x 4 nt, XCD-chunked by s
  int t = blockIdx.x;
  int swz = (t & 7) * 512 + (t >> 3);     // bijective, 4096 % 8 == 0
  int s = swz >> 7;
  int mt = (swz >> 2) & 31;
  int nt = swz & 3;
  int b0 = mt * 128, n0 = nt * 128;
  const short* Asrc = xb + (size_t)b0 * SD + s * ND;              // LD = SD
  const short* Bsrc = G + (size_t)s * ND * ND + (size_t)n0 * ND;  // LD = ND

  __shared__ __align__(16) short lsA[128 * 64];
  __shared__ __align__(16) short lsB[128 * 64];

  int tid = threadIdx.x;
  int lane = tid & 63, wid = tid >> 6;
  int wr = wid >> 1, wc = wid & 1;
  int lhi = lane >> 4, llo = lane & 15;
  int lrow = lane >> 3, lcol = (lane & 7) * 8;

  f4v acc[4][4];
#pragma unroll
  for (int i = 0; i < 4; ++i)
#pragma unroll
    for (int j = 0; j < 4; ++j) acc[i][j] = (f4v)0.0f;

  for (int kt = 0; kt < 8; ++kt) {
    int k0 = kt * 64;
#pragma unroll
    for (int c = 0; c < 4; ++c) {
      int chunk = wid * 4 + c;                 // 0..15, 8 rows each
      int row = chunk * 8 + lrow;
      gload16(Asrc + (size_t)row * SD + k0 + lcol, (char*)lsA + chunk * 1024);
      gload16(Bsrc + (size_t)row * ND + k0 + lcol, (char*)lsB + chunk * 1024);
    }
    __syncthreads();  // drains vmcnt -> tile resident
    const s8v* fA = (const s8v*)lsA;
    const s8v* fB = (const s8v*)lsB;
#pragma unroll
    for (int kk = 0; kk < 2; ++kk) {
      s8v af[4], bq[4];
#pragma unroll
      for (int i = 0; i < 4; ++i) af[i] = fA[(wr * 64 + i * 16 + llo) * 8 + kk * 4 + lhi];
#pragma unroll
      for (int j = 0; j < 4; ++j) bq[j] = fB[(wc * 64 + j * 16 + llo) * 8 + kk * 4 + lhi];
#pragma unroll
      for (int i = 0; i < 4; ++i)
#pragma unroll
        for (int j = 0; j < 4; ++j) acc[i][j] = MFMA_BF16(af[i], bq[j], acc[i][j]);
    }
    __syncthreads();
  }

  // Fused epilogue: scores[b,s] += sum over this block's n-range of x*T
#pragma unroll
  for (int i = 0; i < 4; ++i)
#pragma unroll
    for (int r = 0; r < 4; ++r) {
      int rowl = wr * 64 + i * 16 + lhi * 4 + r;
      int b = b0 + rowl;
      const short* xr = xb + (size_t)b * SD + s * ND + n0 + wc * 64;
      float v = 0.f;
#pragma unroll
      for (int j = 0; j < 4; ++j) v += bf2f(xr[j * 16 + llo]) * acc[i][j][r];
      v += __shfl_xor(v, 1);
      v += __shfl_xor(v, 2);
      v += __shfl_xor(v, 4);
      v += __shfl_xor(v, 8);
      if (llo == 0) atomicAdd(&scores[b * NS + s], v);
    }
}

// ---------------------------------------------------------------------------
// K4: weights = scores / ||scores||_2 (per row of 32)
// ---------------------------------------------------------------------------
__global__ __launch_bounds__(256) void k_weights(const float* __restrict__ scores,
                                                 float* __restrict__ w) {
  int b = blockIdx.x * 256 + threadIdx.x;
  float sq = 0.f, sc[NS];
#pragma unroll
  for (int s = 0; s < NS; ++s) { sc[s] = scores[b * NS + s]; sq += sc[s] * sc[s]; }
  float inv = 1.0f / sqrtf(sq);
#pragma unroll
  for (int s = 0; s < NS; ++s) w[b * NS + s] = sc[s] * inv;
}

// ---------------------------------------------------------------------------
// K4b: xb *= w[b,s] in place (becomes xw)
// ---------------------------------------------------------------------------
__global__ __launch_bounds__(256) void k_scale(short* __restrict__ xb,
                                               const float* __restrict__ wts) {
  size_t i = ((size_t)blockIdx.x * 256 + threadIdx.x) * 8;
  size_t stride = (size_t)gridDim.x * 256 * 8;
  size_t total = (size_t)NB * SD;
  for (; i < total; i += stride) {
    int b = (int)(i >> 14);          // / SD
    int s = (int)((i >> 9) & 31);    // (i % SD) / ND
    float w = wts[b * NS + s];
    s8v v = *(s8v*)(xb + i);
#pragma unroll
    for (int u = 0; u < 8; ++u) v[u] = f2bf(bf2f(v[u]) * w);
    *(s8v*)(xb + i) = v;
  }
}

// ---------------------------------------------------------------------------
// K5: y += xw @ Vt^T   (pure GEMM, 128x128 tile, BK=64, split-K 8 groups)
// ---------------------------------------------------------------------------
__global__ __launch_bounds__(256, 3) void k_out(const short* __restrict__ xw,
                                                const short* __restrict__ Vt,
                                                float* __restrict__ y) {
  // grid 1024 = 32 mt x 4 nt x 8 kg, XCD-chunked by mt
  int t = blockIdx.x;
  int swz = (t & 7) * 128 + (t >> 3);     // bijective, 1024 % 8 == 0
  int mt = swz >> 5;
  int nt = (swz >> 3) & 3;
  int kg = swz & 7;
  int b0 = mt * 128, n0 = nt * 128;
  const short* Asrc = xw + (size_t)b0 * SD + kg * 2048;  // LD = SD
  const short* Bsrc = Vt + (size_t)n0 * SD + kg * 2048;  // LD = SD

  __shared__ __align__(16) short lsA[128 * 64];
  __shared__ __align__(16) short lsB[128 * 64];

  int tid = threadIdx.x;
  int lane = tid & 63, wid = tid >> 6;
  int wr = wid >> 1, wc = wid & 1;
  int lhi = lane >> 4, llo = lane & 15;
  int lrow = lane >> 3, lcol = (lane & 7) * 8;

  f4v acc[4][4];
#pragma unroll
  for (int i = 0; i < 4; ++i)
#pragma unroll
    for (int j = 0; j < 4; ++j) acc[i][j] = (f4v)0.0f;

  for (int kt = 0; kt < 32; ++kt) {
    int k0 = kt * 64;
#pragma unroll
    for (int c = 0; c < 4; ++c) {
      int chunk = wid * 4 + c;                 // 0..15, 8 rows each
      int row = chunk * 8 + lrow;
      gload16(Asrc + (size_t)row * SD + k0 + lcol, (char*)lsA + chunk * 1024);
      gload16(Bsrc + (size_t)row * SD + k0 + lcol, (char*)lsB + chunk * 1024);
    }
    __syncthreads();
    const s8v* fA = (const s8v*)lsA;
    const s8v* fB = (const s8v*)lsB;
#pragma unroll
    for (int kk = 0; kk < 2; ++kk) {
      s8v af[4], bq[4];
#pragma unroll
      for (int i = 0; i < 4; ++i) af[i] = fA[(wr * 64 + i * 16 + llo) * 8 + kk * 4 + lhi];
#pragma unroll
      for (int j = 0; j < 4; ++j) bq[j] = fB[(wc * 64 + j * 16 + llo) * 8 + kk * 4 + lhi];
#pragma unroll
      for (int i = 0; i < 4; ++i)
#pragma unroll
        for (int j = 0; j < 4; ++j) acc[i][j] = MFMA_BF16(af[i], bq[j], acc[i][j]);
    }
    __syncthreads();
  }

#pragma unroll
  for (int i = 0; i < 4; ++i)
#pragma unroll
    for (int r = 0; r < 4; ++r) {
      int row = b0 + wr * 64 + i * 16 + lhi * 4 + r;
#pragma unroll
      for (int j = 0; j < 4; ++j) {
        int col = n0 + wc * 64 + j * 16 + llo;
        atomicAdd(&y[(size_t)row * NE + col], acc[i][j][r]);
      }
    }
}

// ---------------------------------------------------------------------------
extern "C" void kernel_launch(void* const* d_in, const int* in_sizes, int n_in,
                              void* d_out, int out_size, void* d_ws, size_t ws_size,
                              hipStream_t stream) {
  const float* x  = (const float*)d_in[0];
  const float* Qw = (const float*)d_in[1];
  const float* Kw = (const float*)d_in[2];
  const float* Vw = (const float*)d_in[3];
  float* y = (float*)d_out;

  char* ws = (char*)d_ws;
  short* xb     = (short*)ws;                                    // 128 MiB
  short* G      = (short*)(ws + (size_t)128 * 1024 * 1024);      // 16 MiB
  short* Vt     = (short*)(ws + (size_t)144 * 1024 * 1024);      // 16 MiB
  float* scores = (float*)(ws + (size_t)160 * 1024 * 1024);      // 512 KiB
  float* wts    = (float*)(ws + (size_t)160 * 1024 * 1024 + 512 * 1024);

  hipMemsetAsync(scores, 0, (size_t)NB * NS * sizeof(float), stream);
  hipMemsetAsync(y, 0, (size_t)NB * NE * sizeof(float), stream);
  k_castx<<<2048, 256, 0, stream>>>(x, xb);
  k_transposeV<<<dim3(SD / 64, NE / 64), 256, 0, stream>>>(Vw, Vt);
  k_gram<<<dim3(16, NS), 256, 0, stream>>>(Kw, Qw, G);
  k_scores<<<4096, 256, 0, stream>>>(xb, G, scores);
  k_weights<<<NB / 256, 256, 0, stream>>>(scores, wts);
  k_scale<<<2048, 256, 0, stream>>>(xb, wts);
  k_out<<<1024, 256, 0, stream>>>(xb, Vt, y);
}

// Round 4
// 420.055 us; speedup vs baseline: 1.5607x; 1.0191x over previous
//
#include <hip/hip_runtime.h>
#include <hip/hip_bf16.h>
#include <math.h>

// ---------------------------------------------------------------------------
// AttentionBlock: y[b,e] = sum_s w[b,s] * (x_bs @ V_s),
//   w = scores / ||scores||_2,  scores[b,s] = x_bs^T (Q_s K_s^T) x_bs
// Round 4: remove in-graph hipMemsetAsync (each cost ~155us as a rocclr fill
// kernel!). scores zeroed inside k_castx; y zeroed inside k_scale. Same-stream
// kernel ordering guarantees zero-before-atomic. Everything else unchanged.
// ---------------------------------------------------------------------------

typedef __attribute__((ext_vector_type(8))) short s8v;   // 8 x bf16 bits
typedef __attribute__((ext_vector_type(4))) float f4v;   // 4 x f32

#define MFMA_BF16(a, b, c) __builtin_amdgcn_mfma_f32_16x16x32_bf16((a), (b), (c), 0, 0, 0)

constexpr int NB = 4096;     // batch
constexpr int NS = 32;       // segments
constexpr int ND = 512;      // d per segment
constexpr int NE = 512;      // e (output dim)
constexpr int SD = NS * ND;  // 16384

__device__ __forceinline__ short f2bf(float f) {
  union { float f; unsigned u; } v; v.f = f;
  unsigned r = v.u + 0x7fffu + ((v.u >> 16) & 1u);  // RNE
  return (short)(r >> 16);
}
__device__ __forceinline__ float bf2f(short h) {
  union { unsigned u; float f; } v; v.u = ((unsigned)(unsigned short)h) << 16;
  return v.f;
}
__device__ __forceinline__ s8v cvt8(const float* p) {
  s8v r;
#pragma unroll
  for (int i = 0; i < 8; ++i) r[i] = f2bf(p[i]);
  return r;
}

// global -> LDS direct (16B per lane). LDS base must be wave-uniform.
__device__ __forceinline__ void gload16(const void* g, void* l) {
  __builtin_amdgcn_global_load_lds(
      (const __attribute__((address_space(1))) unsigned int*)g,
      (__attribute__((address_space(3))) unsigned int*)l, 16, 0, 0);
}

// ---------------------------------------------------------------------------
// K_cast: x f32 -> xb bf16 (grid-stride, 8 elems/thread/iter) + zero scores
// ---------------------------------------------------------------------------
__global__ __launch_bounds__(256) void k_castx(const float* __restrict__ x,
                                               short* __restrict__ xb,
                                               float* __restrict__ scores) {
  size_t gtid = (size_t)blockIdx.x * 256 + threadIdx.x;
  if (gtid < (size_t)NB * NS / 4) {           // 32768 threads x 4 floats
    f4v z = (f4v)0.0f;
    *(f4v*)(scores + gtid * 4) = z;
  }
  size_t i = gtid * 8;
  size_t stride = (size_t)gridDim.x * 256 * 8;
  size_t total = (size_t)NB * SD;
  for (; i < total; i += stride) {
    f4v a = *(const f4v*)(x + i);
    f4v b = *(const f4v*)(x + i + 4);
    s8v o;
#pragma unroll
    for (int u = 0; u < 4; ++u) { o[u] = f2bf(a[u]); o[4 + u] = f2bf(b[u]); }
    *(s8v*)(xb + i) = o;
  }
}

// ---------------------------------------------------------------------------
// K1: V [SD, NE] f32  ->  Vt [NE, SD] bf16
// ---------------------------------------------------------------------------
__global__ __launch_bounds__(256) void k_transposeV(const float* __restrict__ V,
                                                    short* __restrict__ Vt) {
  __shared__ float t[64][65];
  int k0 = blockIdx.x * 64;
  int e0 = blockIdx.y * 64;
  int tid = threadIdx.x;
#pragma unroll
  for (int i = 0; i < 16; ++i) {
    int idx = tid + 256 * i;
    int r = idx >> 6, c = idx & 63;
    t[r][c] = V[(size_t)(k0 + r) * NE + e0 + c];
  }
  __syncthreads();
#pragma unroll
  for (int i = 0; i < 16; ++i) {
    int idx = tid + 256 * i;
    int e = idx >> 6, k = idx & 63;
    Vt[(size_t)(e0 + e) * SD + k0 + k] = f2bf(t[k][e]);
  }
}

// ---------------------------------------------------------------------------
// K2: G_s[i][j] = sum_e K_s[i,e] * Q_s[j,e]   (128x128 tile, BK=64, f32 in)
// ---------------------------------------------------------------------------
__global__ __launch_bounds__(256) void k_gram(const float* __restrict__ Kw,
                                              const float* __restrict__ Qw,
                                              short* __restrict__ G) {
  int s = blockIdx.y;
  int tm = blockIdx.x >> 2, tn = blockIdx.x & 3;
  const float* A = Kw + (size_t)s * ND * NE + (size_t)tm * 128 * NE;
  const float* B = Qw + (size_t)s * ND * NE + (size_t)tn * 128 * NE;
  short* Gs = G + (size_t)s * ND * ND;

  __shared__ s8v lsA[128][9];
  __shared__ s8v lsB[128][9];

  int tid = threadIdx.x;
  int lane = tid & 63, wid = tid >> 6;
  int wr = wid >> 1, wc = wid & 1;
  int lhi = lane >> 4, llo = lane & 15;

  float ra[4][8], rb[4][8];
  f4v acc[4][4];
#pragma unroll
  for (int i = 0; i < 4; ++i)
#pragma unroll
    for (int j = 0; j < 4; ++j) acc[i][j] = (f4v)0.0f;

  auto loadRegs = [&](int k0) {
#pragma unroll
    for (int i = 0; i < 4; ++i) {
      int c = tid + 256 * i; int row = c >> 3, k8 = c & 7;
      const float* p = A + (size_t)row * NE + k0 + k8 * 8;
      *(f4v*)&ra[i][0] = *(const f4v*)p;
      *(f4v*)&ra[i][4] = *(const f4v*)(p + 4);
      const float* q = B + (size_t)row * NE + k0 + k8 * 8;
      *(f4v*)&rb[i][0] = *(const f4v*)q;
      *(f4v*)&rb[i][4] = *(const f4v*)(q + 4);
    }
  };
  auto writeLds = [&]() {
#pragma unroll
    for (int i = 0; i < 4; ++i) {
      int c = tid + 256 * i; int row = c >> 3, k8 = c & 7;
      lsA[row][k8] = cvt8(ra[i]);
      lsB[row][k8] = cvt8(rb[i]);
    }
  };

  loadRegs(0);
  writeLds();
  for (int kt = 0; kt < 8; ++kt) {
    __syncthreads();
    if (kt + 1 < 8) loadRegs((kt + 1) * 64);
#pragma unroll
    for (int kk = 0; kk < 2; ++kk) {
      s8v af[4], bq[4];
#pragma unroll
      for (int i = 0; i < 4; ++i) af[i] = lsA[wr * 64 + i * 16 + llo][kk * 4 + lhi];
#pragma unroll
      for (int j = 0; j < 4; ++j) bq[j] = lsB[wc * 64 + j * 16 + llo][kk * 4 + lhi];
#pragma unroll
      for (int i = 0; i < 4; ++i)
#pragma unroll
        for (int j = 0; j < 4; ++j) acc[i][j] = MFMA_BF16(af[i], bq[j], acc[i][j]);
    }
    __syncthreads();
    if (kt + 1 < 8) writeLds();
  }

#pragma unroll
  for (int i = 0; i < 4; ++i)
#pragma unroll
    for (int r = 0; r < 4; ++r) {
      int row = tm * 128 + wr * 64 + i * 16 + lhi * 4 + r;
#pragma unroll
      for (int j = 0; j < 4; ++j) {
        int col = tn * 128 + wc * 64 + j * 16 + llo;
        Gs[(size_t)row * ND + col] = f2bf(acc[i][j][r]);
      }
    }
}

// ---------------------------------------------------------------------------
// K3: T = Xb_s @ W, scores[b,s] += sum_n Xb_s[b,n]*T[b,n]
//     128x128 tile, BK=64, pure bf16, global_load_lds, single-buffer
// ---------------------------------------------------------------------------
__global__ __launch_bounds__(256, 3) void k_scores(const short* __restrict__ xb,
                                                   const short* __restrict__ G,
                                                   float* __restrict__ scores) {
  // grid 4096 = 32 s x 32 mt x 4 nt, XCD-chunked by s
  int t = blockIdx.x;
  int swz = (t & 7) * 512 + (t >> 3);     // bijective, 4096 % 8 == 0
  int s = swz >> 7;
  int mt = (swz >> 2) & 31;
  int nt = swz & 3;
  int b0 = mt * 128, n0 = nt * 128;
  const short* Asrc = xb + (size_t)b0 * SD + s * ND;              // LD = SD
  const short* Bsrc = G + (size_t)s * ND * ND + (size_t)n0 * ND;  // LD = ND

  __shared__ __align__(16) short lsA[128 * 64];
  __shared__ __align__(16) short lsB[128 * 64];

  int tid = threadIdx.x;
  int lane = tid & 63, wid = tid >> 6;
  int wr = wid >> 1, wc = wid & 1;
  int lhi = lane >> 4, llo = lane & 15;
  int lrow = lane >> 3, lcol = (lane & 7) * 8;

  f4v acc[4][4];
#pragma unroll
  for (int i = 0; i < 4; ++i)
#pragma unroll
    for (int j = 0; j < 4; ++j) acc[i][j] = (f4v)0.0f;

  for (int kt = 0; kt < 8; ++kt) {
    int k0 = kt * 64;
#pragma unroll
    for (int c = 0; c < 4; ++c) {
      int chunk = wid * 4 + c;                 // 0..15, 8 rows each
      int row = chunk * 8 + lrow;
      gload16(Asrc + (size_t)row * SD + k0 + lcol, (char*)lsA + chunk * 1024);
      gload16(Bsrc + (size_t)row * ND + k0 + lcol, (char*)lsB + chunk * 1024);
    }
    __syncthreads();  // drains vmcnt -> tile resident
    const s8v* fA = (const s8v*)lsA;
    const s8v* fB = (const s8v*)lsB;
#pragma unroll
    for (int kk = 0; kk < 2; ++kk) {
      s8v af[4], bq[4];
#pragma unroll
      for (int i = 0; i < 4; ++i) af[i] = fA[(wr * 64 + i * 16 + llo) * 8 + kk * 4 + lhi];
#pragma unroll
      for (int j = 0; j < 4; ++j) bq[j] = fB[(wc * 64 + j * 16 + llo) * 8 + kk * 4 + lhi];
#pragma unroll
      for (int i = 0; i < 4; ++i)
#pragma unroll
        for (int j = 0; j < 4; ++j) acc[i][j] = MFMA_BF16(af[i], bq[j], acc[i][j]);
    }
    __syncthreads();
  }

  // Fused epilogue: scores[b,s] += sum over this block's n-range of x*T
#pragma unroll
  for (int i = 0; i < 4; ++i)
#pragma unroll
    for (int r = 0; r < 4; ++r) {
      int rowl = wr * 64 + i * 16 + lhi * 4 + r;
      int b = b0 + rowl;
      const short* xr = xb + (size_t)b * SD + s * ND + n0 + wc * 64;
      float v = 0.f;
#pragma unroll
      for (int j = 0; j < 4; ++j) v += bf2f(xr[j * 16 + llo]) * acc[i][j][r];
      v += __shfl_xor(v, 1);
      v += __shfl_xor(v, 2);
      v += __shfl_xor(v, 4);
      v += __shfl_xor(v, 8);
      if (llo == 0) atomicAdd(&scores[b * NS + s], v);
    }
}

// ---------------------------------------------------------------------------
// K4: weights = scores / ||scores||_2 (per row of 32)
// ---------------------------------------------------------------------------
__global__ __launch_bounds__(256) void k_weights(const float* __restrict__ scores,
                                                 float* __restrict__ w) {
  int b = blockIdx.x * 256 + threadIdx.x;
  float sq = 0.f, sc[NS];
#pragma unroll
  for (int s = 0; s < NS; ++s) { sc[s] = scores[b * NS + s]; sq += sc[s] * sc[s]; }
  float inv = 1.0f / sqrtf(sq);
#pragma unroll
  for (int s = 0; s < NS; ++s) w[b * NS + s] = sc[s] * inv;
}

// ---------------------------------------------------------------------------
// K4b: xb *= w[b,s] in place (becomes xw) + zero y
// ---------------------------------------------------------------------------
__global__ __launch_bounds__(256) void k_scale(short* __restrict__ xb,
                                               const float* __restrict__ wts,
                                               float* __restrict__ y) {
  size_t gtid = (size_t)blockIdx.x * 256 + threadIdx.x;
  {  // zero y: 524288 threads x 4 floats = 2M = NB*NE
    f4v z = (f4v)0.0f;
    *(f4v*)(y + gtid * 4) = z;
  }
  size_t i = gtid * 8;
  size_t stride = (size_t)gridDim.x * 256 * 8;
  size_t total = (size_t)NB * SD;
  for (; i < total; i += stride) {
    int b = (int)(i >> 14);          // / SD
    int s = (int)((i >> 9) & 31);    // (i % SD) / ND
    float w = wts[b * NS + s];
    s8v v = *(s8v*)(xb + i);
#pragma unroll
    for (int u = 0; u < 8; ++u) v[u] = f2bf(bf2f(v[u]) * w);
    *(s8v*)(xb + i) = v;
  }
}

// ---------------------------------------------------------------------------
// K5: y += xw @ Vt^T   (pure GEMM, 128x128 tile, BK=64, split-K 8 groups)
// ---------------------------------------------------------------------------
__global__ __launch_bounds__(256, 3) void k_out(const short* __restrict__ xw,
                                                const short* __restrict__ Vt,
                                                float* __restrict__ y) {
  // grid 1024 = 32 mt x 4 nt x 8 kg, XCD-chunked by mt
  int t = blockIdx.x;
  int swz = (t & 7) * 128 + (t >> 3);     // bijective, 1024 % 8 == 0
  int mt = swz >> 5;
  int nt = (swz >> 3) & 3;
  int kg = swz & 7;
  int b0 = mt * 128, n0 = nt * 128;
  const short* Asrc = xw + (size_t)b0 * SD + kg * 2048;  // LD = SD
  const short* Bsrc = Vt + (size_t)n0 * SD + kg * 2048;  // LD = SD

  __shared__ __align__(16) short lsA[128 * 64];
  __shared__ __align__(16) short lsB[128 * 64];

  int tid = threadIdx.x;
  int lane = tid & 63, wid = tid >> 6;
  int wr = wid >> 1, wc = wid & 1;
  int lhi = lane >> 4, llo = lane & 15;
  int lrow = lane >> 3, lcol = (lane & 7) * 8;

  f4v acc[4][4];
#pragma unroll
  for (int i = 0; i < 4; ++i)
#pragma unroll
    for (int j = 0; j < 4; ++j) acc[i][j] = (f4v)0.0f;

  for (int kt = 0; kt < 32; ++kt) {
    int k0 = kt * 64;
#pragma unroll
    for (int c = 0; c < 4; ++c) {
      int chunk = wid * 4 + c;                 // 0..15, 8 rows each
      int row = chunk * 8 + lrow;
      gload16(Asrc + (size_t)row * SD + k0 + lcol, (char*)lsA + chunk * 1024);
      gload16(Bsrc + (size_t)row * SD + k0 + lcol, (char*)lsB + chunk * 1024);
    }
    __syncthreads();
    const s8v* fA = (const s8v*)lsA;
    const s8v* fB = (const s8v*)lsB;
#pragma unroll
    for (int kk = 0; kk < 2; ++kk) {
      s8v af[4], bq[4];
#pragma unroll
      for (int i = 0; i < 4; ++i) af[i] = fA[(wr * 64 + i * 16 + llo) * 8 + kk * 4 + lhi];
#pragma unroll
      for (int j = 0; j < 4; ++j) bq[j] = fB[(wc * 64 + j * 16 + llo) * 8 + kk * 4 + lhi];
#pragma unroll
      for (int i = 0; i < 4; ++i)
#pragma unroll
        for (int j = 0; j < 4; ++j) acc[i][j] = MFMA_BF16(af[i], bq[j], acc[i][j]);
    }
    __syncthreads();
  }

#pragma unroll
  for (int i = 0; i < 4; ++i)
#pragma unroll
    for (int r = 0; r < 4; ++r) {
      int row = b0 + wr * 64 + i * 16 + lhi * 4 + r;
#pragma unroll
      for (int j = 0; j < 4; ++j) {
        int col = n0 + wc * 64 + j * 16 + llo;
        atomicAdd(&y[(size_t)row * NE + col], acc[i][j][r]);
      }
    }
}

// ---------------------------------------------------------------------------
extern "C" void kernel_launch(void* const* d_in, const int* in_sizes, int n_in,
                              void* d_out, int out_size, void* d_ws, size_t ws_size,
                              hipStream_t stream) {
  const float* x  = (const float*)d_in[0];
  const float* Qw = (const float*)d_in[1];
  const float* Kw = (const float*)d_in[2];
  const float* Vw = (const float*)d_in[3];
  float* y = (float*)d_out;

  char* ws = (char*)d_ws;
  short* xb     = (short*)ws;                                    // 128 MiB
  short* G      = (short*)(ws + (size_t)128 * 1024 * 1024);      // 16 MiB
  short* Vt     = (short*)(ws + (size_t)144 * 1024 * 1024);      // 16 MiB
  float* scores = (float*)(ws + (size_t)160 * 1024 * 1024);      // 512 KiB
  float* wts    = (float*)(ws + (size_t)160 * 1024 * 1024 + 512 * 1024);

  k_castx<<<2048, 256, 0, stream>>>(x, xb, scores);
  k_transposeV<<<dim3(SD / 64, NE / 64), 256, 0, stream>>>(Vw, Vt);
  k_gram<<<dim3(16, NS), 256, 0, stream>>>(Kw, Qw, G);
  k_scores<<<4096, 256, 0, stream>>>(xb, G, scores);
  k_weights<<<NB / 256, 256, 0, stream>>>(scores, wts);
  k_scale<<<2048, 256, 0, stream>>>(xb, wts, y);
  k_out<<<1024, 256, 0, stream>>>(xb, Vt, y);
}

// Round 6
// 399.708 us; speedup vs baseline: 1.6401x; 1.0509x over previous
//
#include <hip/hip_runtime.h>
#include <hip/hip_bf16.h>
#include <math.h>

// ---------------------------------------------------------------------------
// AttentionBlock: y[b,e] = sum_s w[b,s] * (x_bs @ V_s),
//   w = scores / ||scores||_2,  scores[b,s] = x_bs^T (Q_s K_s^T) x_bs
// Round 6 (= Round 5 with two bugfixes):
//   - k_symm LDS staging: store tt[r][c] naturally; read tt[c][r] = G[b][a].
//   - k_scores triangular K-loop direction: kt in [2*nt, 8) (U[n][k] != 0
//     only for k >= n), was [0, 2*(nt+1)).
// Plan: scores = x^T U x with U = upper(G+G^T); 20/32 of k-tiles skipped.
// ---------------------------------------------------------------------------

typedef __attribute__((ext_vector_type(8))) short s8v;   // 8 x bf16 bits
typedef __attribute__((ext_vector_type(4))) float f4v;   // 4 x f32

#define MFMA_BF16(a, b, c) __builtin_amdgcn_mfma_f32_16x16x32_bf16((a), (b), (c), 0, 0, 0)

constexpr int NB = 4096;     // batch
constexpr int NS = 32;       // segments
constexpr int ND = 512;      // d per segment
constexpr int NE = 512;      // e (output dim)
constexpr int SD = NS * ND;  // 16384

__device__ __forceinline__ short f2bf(float f) {
  union { float f; unsigned u; } v; v.f = f;
  unsigned r = v.u + 0x7fffu + ((v.u >> 16) & 1u);  // RNE
  return (short)(r >> 16);
}
__device__ __forceinline__ float bf2f(short h) {
  union { unsigned u; float f; } v; v.u = ((unsigned)(unsigned short)h) << 16;
  return v.f;
}
__device__ __forceinline__ s8v cvt8(const float* p) {
  s8v r;
#pragma unroll
  for (int i = 0; i < 8; ++i) r[i] = f2bf(p[i]);
  return r;
}

// global -> LDS direct (16B per lane). LDS base must be wave-uniform.
__device__ __forceinline__ void gload16(const void* g, void* l) {
  __builtin_amdgcn_global_load_lds(
      (const __attribute__((address_space(1))) unsigned int*)g,
      (__attribute__((address_space(3))) unsigned int*)l, 16, 0, 0);
}

// ---------------------------------------------------------------------------
// K_prep: fused  [0,2048) castx + zero-scores | [2048,4096) transposeV |
//                [4096,4608) gram
// ---------------------------------------------------------------------------
__global__ __launch_bounds__(256) void k_prep(const float* __restrict__ x,
                                              short* __restrict__ xb,
                                              float* __restrict__ scores,
                                              const float* __restrict__ V,
                                              short* __restrict__ Vt,
                                              const float* __restrict__ Kw,
                                              const float* __restrict__ Qw,
                                              short* __restrict__ G) {
  __shared__ __align__(16) char smem[36864];
  int bid = blockIdx.x;
  int tid = threadIdx.x;

  if (bid < 2048) {
    // ---- castx: x f32 -> xb bf16, plus zero scores ----
    size_t gtid = (size_t)bid * 256 + tid;
    if (gtid < (size_t)NB * NS / 4) {
      f4v z = (f4v)0.0f;
      *(f4v*)(scores + gtid * 4) = z;
    }
    size_t i = gtid * 8;
    size_t stride = (size_t)2048 * 256 * 8;
    size_t total = (size_t)NB * SD;
    for (; i < total; i += stride) {
      f4v a = *(const f4v*)(x + i);
      f4v b = *(const f4v*)(x + i + 4);
      s8v o;
#pragma unroll
      for (int u = 0; u < 4; ++u) { o[u] = f2bf(a[u]); o[4 + u] = f2bf(b[u]); }
      *(s8v*)(xb + i) = o;
    }
  } else if (bid < 4096) {
    // ---- transposeV: V [SD,NE] f32 -> Vt [NE,SD] bf16 ----
    float (*t)[65] = (float(*)[65])smem;
    int t2 = bid - 2048;
    int k0 = (t2 & 255) * 64;
    int e0 = (t2 >> 8) * 64;
#pragma unroll
    for (int i = 0; i < 16; ++i) {
      int idx = tid + 256 * i;
      int r = idx >> 6, c = idx & 63;
      t[r][c] = V[(size_t)(k0 + r) * NE + e0 + c];
    }
    __syncthreads();
#pragma unroll
    for (int i = 0; i < 16; ++i) {
      int idx = tid + 256 * i;
      int e = idx >> 6, k = idx & 63;
      Vt[(size_t)(e0 + e) * SD + k0 + k] = f2bf(t[k][e]);
    }
  } else {
    // ---- gram: G_s[i][j] = sum_e K_s[i,e] * Q_s[j,e], 128x128 tile ----
    int t3 = bid - 4096;
    int s = t3 >> 4;
    int tm = (t3 >> 2) & 3, tn = t3 & 3;
    const float* A = Kw + (size_t)s * ND * NE + (size_t)tm * 128 * NE;
    const float* B = Qw + (size_t)s * ND * NE + (size_t)tn * 128 * NE;
    short* Gs = G + (size_t)s * ND * ND;

    s8v (*lsA)[9] = (s8v(*)[9])smem;
    s8v (*lsB)[9] = (s8v(*)[9])(smem + 18432);

    int lane = tid & 63, wid = tid >> 6;
    int wr = wid >> 1, wc = wid & 1;
    int lhi = lane >> 4, llo = lane & 15;

    float ra[4][8], rb[4][8];
    f4v acc[4][4];
#pragma unroll
    for (int i = 0; i < 4; ++i)
#pragma unroll
      for (int j = 0; j < 4; ++j) acc[i][j] = (f4v)0.0f;

    auto loadRegs = [&](int k0) {
#pragma unroll
      for (int i = 0; i < 4; ++i) {
        int c = tid + 256 * i; int row = c >> 3, k8 = c & 7;
        const float* p = A + (size_t)row * NE + k0 + k8 * 8;
        *(f4v*)&ra[i][0] = *(const f4v*)p;
        *(f4v*)&ra[i][4] = *(const f4v*)(p + 4);
        const float* q = B + (size_t)row * NE + k0 + k8 * 8;
        *(f4v*)&rb[i][0] = *(const f4v*)q;
        *(f4v*)&rb[i][4] = *(const f4v*)(q + 4);
      }
    };
    auto writeLds = [&]() {
#pragma unroll
      for (int i = 0; i < 4; ++i) {
        int c = tid + 256 * i; int row = c >> 3, k8 = c & 7;
        lsA[row][k8] = cvt8(ra[i]);
        lsB[row][k8] = cvt8(rb[i]);
      }
    };

    loadRegs(0);
    writeLds();
    for (int kt = 0; kt < 8; ++kt) {
      __syncthreads();
      if (kt + 1 < 8) loadRegs((kt + 1) * 64);
#pragma unroll
      for (int kk = 0; kk < 2; ++kk) {
        s8v af[4], bq[4];
#pragma unroll
        for (int i = 0; i < 4; ++i) af[i] = lsA[wr * 64 + i * 16 + llo][kk * 4 + lhi];
#pragma unroll
        for (int j = 0; j < 4; ++j) bq[j] = lsB[wc * 64 + j * 16 + llo][kk * 4 + lhi];
#pragma unroll
        for (int i = 0; i < 4; ++i)
#pragma unroll
          for (int j = 0; j < 4; ++j) acc[i][j] = MFMA_BF16(af[i], bq[j], acc[i][j]);
      }
      __syncthreads();
      if (kt + 1 < 8) writeLds();
    }

#pragma unroll
    for (int i = 0; i < 4; ++i)
#pragma unroll
      for (int r = 0; r < 4; ++r) {
        int row = tm * 128 + wr * 64 + i * 16 + lhi * 4 + r;
#pragma unroll
        for (int j = 0; j < 4; ++j) {
          int col = tn * 128 + wc * 64 + j * 16 + llo;
          Gs[(size_t)row * ND + col] = f2bf(acc[i][j][r]);
        }
      }
  }
}

// ---------------------------------------------------------------------------
// K_symm: U[a][b] = a<b ? G[a][b]+G[b][a] : (a==b ? G[a][a] : 0)
//   grid (64 tiles of 64x64, 32 segments). a = k0+r rows, b = n0+c cols.
// ---------------------------------------------------------------------------
__global__ __launch_bounds__(256) void k_symm(const short* __restrict__ G,
                                              short* __restrict__ U) {
  int s = blockIdx.y;
  int kt = blockIdx.x >> 3, nt = blockIdx.x & 7;
  const short* Gs = G + (size_t)s * ND * ND;
  short* Us = U + (size_t)s * ND * ND;
  int k0 = kt * 64, n0 = nt * 64;
  int tid = threadIdx.x;
  int r = tid >> 2, cb = (tid & 3) * 16;

  if (kt > nt) {  // strictly below diagonal: zero
    s8v z = (s8v)(short)0;
    *(s8v*)&Us[(size_t)(k0 + r) * ND + n0 + cb] = z;
    *(s8v*)&Us[(size_t)(k0 + r) * ND + n0 + cb + 8] = z;
    return;
  }

  // tt[j][i] = G[n0+j][k0+i]  (natural row-major store of the (b,a) tile)
  __shared__ float tt[64][65];
  {
    const short* src = &Gs[(size_t)(n0 + r) * ND + k0 + cb];
    s8v a = *(const s8v*)src;
    s8v b = *(const s8v*)(src + 8);
#pragma unroll
    for (int u = 0; u < 8; ++u) { tt[r][cb + u] = bf2f(a[u]); tt[r][cb + 8 + u] = bf2f(b[u]); }
  }
  __syncthreads();
  {
    const short* src = &Gs[(size_t)(k0 + r) * ND + n0 + cb];
    s8v a = *(const s8v*)src;
    s8v b = *(const s8v*)(src + 8);
    s8v oa, ob;
#pragma unroll
    for (int u = 0; u < 8; ++u) {
      int k = k0 + r;
      int n1 = n0 + cb + u, n2 = n0 + cb + 8 + u;
      float g1 = bf2f(a[u]), g2 = bf2f(b[u]);
      // G[b][a] = G[n1][k] = tt[cb+u][r]  (column read, stride 65: bank-safe)
      float v1 = (k < n1) ? (g1 + tt[cb + u][r]) : ((k == n1) ? g1 : 0.f);
      float v2 = (k < n2) ? (g2 + tt[cb + 8 + u][r]) : ((k == n2) ? g2 : 0.f);
      oa[u] = f2bf(v1); ob[u] = f2bf(v2);
    }
    short* dst = &Us[(size_t)(k0 + r) * ND + n0 + cb];
    *(s8v*)dst = oa;
    *(s8v*)(dst + 8) = ob;
  }
}

// ---------------------------------------------------------------------------
// K3: T = Xb_s @ W with W[k][n] = U[n][k] (nonzero for k >= n),
//     scores[b,s] += sum_n Xb_s[b,n]*T[b,n]
//     128x128 tile, BK=64, triangular K-loop: kt in [2*nt, 8)
// ---------------------------------------------------------------------------
__global__ __launch_bounds__(256, 4) void k_scores(const short* __restrict__ xb,
                                                   const short* __restrict__ U,
                                                   float* __restrict__ scores) {
  // grid 4096 = 32 s x 32 mt x 4 nt, XCD-chunked
  int t = blockIdx.x;
  int swz = (t & 7) * 512 + (t >> 3);     // bijective, 4096 % 8 == 0
  int s = swz >> 7;
  int mt = (swz >> 2) & 31;
  int nt = swz & 3;
  int b0 = mt * 128, n0 = nt * 128;
  const short* Asrc = xb + (size_t)b0 * SD + s * ND;              // LD = SD
  const short* Bt = U + (size_t)s * ND * ND + (size_t)n0 * ND;    // rows = n, LD = ND over k

  __shared__ __align__(16) short lsA[128 * 64];
  __shared__ __align__(16) short lsB[128 * 64];

  int tid = threadIdx.x;
  int lane = tid & 63, wid = tid >> 6;
  int wr = wid >> 1, wc = wid & 1;
  int lhi = lane >> 4, llo = lane & 15;
  int lrow = lane >> 3, lcol = (lane & 7) * 8;

  f4v acc[4][4];
#pragma unroll
  for (int i = 0; i < 4; ++i)
#pragma unroll
    for (int j = 0; j < 4; ++j) acc[i][j] = (f4v)0.0f;

  // U[n][k] nonzero only for k >= n: k-tiles [2*nt, 8)
  for (int kt = 2 * nt; kt < 8; ++kt) {
    int k0 = kt * 64;
#pragma unroll
    for (int c = 0; c < 4; ++c) {
      int chunk = wid * 4 + c;                 // 0..15, 8 rows each
      int row = chunk * 8 + lrow;
      gload16(Asrc + (size_t)row * SD + k0 + lcol, (char*)lsA + chunk * 1024);
      gload16(Bt + (size_t)row * ND + k0 + lcol, (char*)lsB + chunk * 1024);
    }
    __syncthreads();  // drains vmcnt -> tile resident
    const s8v* fA = (const s8v*)lsA;
    const s8v* fB = (const s8v*)lsB;
#pragma unroll
    for (int kk = 0; kk < 2; ++kk) {
      s8v af[4], bq[4];
#pragma unroll
      for (int i = 0; i < 4; ++i) af[i] = fA[(wr * 64 + i * 16 + llo) * 8 + kk * 4 + lhi];
#pragma unroll
      for (int j = 0; j < 4; ++j) bq[j] = fB[(wc * 64 + j * 16 + llo) * 8 + kk * 4 + lhi];
#pragma unroll
      for (int i = 0; i < 4; ++i)
#pragma unroll
        for (int j = 0; j < 4; ++j) acc[i][j] = MFMA_BF16(af[i], bq[j], acc[i][j]);
    }
    __syncthreads();
  }

  // Fused epilogue: scores[b,s] += sum over this block's n-range of x*T
#pragma unroll
  for (int i = 0; i < 4; ++i)
#pragma unroll
    for (int r = 0; r < 4; ++r) {
      int rowl = wr * 64 + i * 16 + lhi * 4 + r;
      int b = b0 + rowl;
      const short* xr = xb + (size_t)b * SD + s * ND + n0 + wc * 64;
      float v = 0.f;
#pragma unroll
      for (int j = 0; j < 4; ++j) v += bf2f(xr[j * 16 + llo]) * acc[i][j][r];
      v += __shfl_xor(v, 1);
      v += __shfl_xor(v, 2);
      v += __shfl_xor(v, 4);
      v += __shfl_xor(v, 8);
      if (llo == 0) atomicAdd(&scores[b * NS + s], v);
    }
}

// ---------------------------------------------------------------------------
// K4: weights = scores / ||scores||_2 (per row of 32)
// ---------------------------------------------------------------------------
__global__ __launch_bounds__(256) void k_weights(const float* __restrict__ scores,
                                                 float* __restrict__ w) {
  int b = blockIdx.x * 256 + threadIdx.x;
  float sq = 0.f, sc[NS];
#pragma unroll
  for (int s = 0; s < NS; ++s) { sc[s] = scores[b * NS + s]; sq += sc[s] * sc[s]; }
  float inv = 1.0f / sqrtf(sq);
#pragma unroll
  for (int s = 0; s < NS; ++s) w[b * NS + s] = sc[s] * inv;
}

// ---------------------------------------------------------------------------
// K4b: xb *= w[b,s] in place (becomes xw) + zero y
// ---------------------------------------------------------------------------
__global__ __launch_bounds__(256) void k_scale(short* __restrict__ xb,
                                               const float* __restrict__ wts,
                                               float* __restrict__ y) {
  size_t gtid = (size_t)blockIdx.x * 256 + threadIdx.x;
  {  // zero y: 524288 threads x 4 floats = 2M = NB*NE
    f4v z = (f4v)0.0f;
    *(f4v*)(y + gtid * 4) = z;
  }
  size_t i = gtid * 8;
  size_t stride = (size_t)gridDim.x * 256 * 8;
  size_t total = (size_t)NB * SD;
  for (; i < total; i += stride) {
    int b = (int)(i >> 14);          // / SD
    int s = (int)((i >> 9) & 31);    // (i % SD) / ND
    float w = wts[b * NS + s];
    s8v v = *(s8v*)(xb + i);
#pragma unroll
    for (int u = 0; u < 8; ++u) v[u] = f2bf(bf2f(v[u]) * w);
    *(s8v*)(xb + i) = v;
  }
}

// ---------------------------------------------------------------------------
// K5: y += xw @ Vt^T   (pure GEMM, 128x128 tile, BK=64, split-K 8 groups)
// ---------------------------------------------------------------------------
__global__ __launch_bounds__(256, 4) void k_out(const short* __restrict__ xw,
                                                const short* __restrict__ Vt,
                                                float* __restrict__ y) {
  // grid 1024 = 32 mt x 4 nt x 8 kg, XCD-chunked
  int t = blockIdx.x;
  int swz = (t & 7) * 128 + (t >> 3);     // bijective, 1024 % 8 == 0
  int mt = swz >> 5;
  int nt = (swz >> 3) & 3;
  int kg = swz & 7;
  int b0 = mt * 128, n0 = nt * 128;
  const short* Asrc = xw + (size_t)b0 * SD + kg * 2048;  // LD = SD
  const short* Bsrc = Vt + (size_t)n0 * SD + kg * 2048;  // LD = SD

  __shared__ __align__(16) short lsA[128 * 64];
  __shared__ __align__(16) short lsB[128 * 64];

  int tid = threadIdx.x;
  int lane = tid & 63, wid = tid >> 6;
  int wr = wid >> 1, wc = wid & 1;
  int lhi = lane >> 4, llo = lane & 15;
  int lrow = lane >> 3, lcol = (lane & 7) * 8;

  f4v acc[4][4];
#pragma unroll
  for (int i = 0; i < 4; ++i)
#pragma unroll
    for (int j = 0; j < 4; ++j) acc[i][j] = (f4v)0.0f;

  for (int kt = 0; kt < 32; ++kt) {
    int k0 = kt * 64;
#pragma unroll
    for (int c = 0; c < 4; ++c) {
      int chunk = wid * 4 + c;                 // 0..15, 8 rows each
      int row = chunk * 8 + lrow;
      gload16(Asrc + (size_t)row * SD + k0 + lcol, (char*)lsA + chunk * 1024);
      gload16(Bsrc + (size_t)row * SD + k0 + lcol, (char*)lsB + chunk * 1024);
    }
    __syncthreads();
    const s8v* fA = (const s8v*)lsA;
    const s8v* fB = (const s8v*)lsB;
#pragma unroll
    for (int kk = 0; kk < 2; ++kk) {
      s8v af[4], bq[4];
#pragma unroll
      for (int i = 0; i < 4; ++i) af[i] = fA[(wr * 64 + i * 16 + llo) * 8 + kk * 4 + lhi];
#pragma unroll
      for (int j = 0; j < 4; ++j) bq[j] = fB[(wc * 64 + j * 16 + llo) * 8 + kk * 4 + lhi];
#pragma unroll
      for (int i = 0; i < 4; ++i)
#pragma unroll
        for (int j = 0; j < 4; ++j) acc[i][j] = MFMA_BF16(af[i], bq[j], acc[i][j]);
    }
    __syncthreads();
  }

#pragma unroll
  for (int i = 0; i < 4; ++i)
#pragma unroll
    for (int r = 0; r < 4; ++r) {
      int row = b0 + wr * 64 + i * 16 + lhi * 4 + r;
#pragma unroll
      for (int j = 0; j < 4; ++j) {
        int col = n0 + wc * 64 + j * 16 + llo;
        atomicAdd(&y[(size_t)row * NE + col], acc[i][j][r]);
      }
    }
}

// ---------------------------------------------------------------------------
extern "C" void kernel_launch(void* const* d_in, const int* in_sizes, int n_in,
                              void* d_out, int out_size, void* d_ws, size_t ws_size,
                              hipStream_t stream) {
  const float* x  = (const float*)d_in[0];
  const float* Qw = (const float*)d_in[1];
  const float* Kw = (const float*)d_in[2];
  const float* Vw = (const float*)d_in[3];
  float* y = (float*)d_out;

  char* ws = (char*)d_ws;
  short* xb     = (short*)ws;                                    // 128 MiB
  short* G      = (short*)(ws + (size_t)128 * 1024 * 1024);      // 16 MiB
  short* Vt     = (short*)(ws + (size_t)144 * 1024 * 1024);      // 16 MiB
  short* Ut     = (short*)(ws + (size_t)160 * 1024 * 1024);      // 16 MiB (U, rows=a)
  float* scores = (float*)(ws + (size_t)176 * 1024 * 1024);      // 512 KiB
  float* wts    = (float*)(ws + (size_t)176 * 1024 * 1024 + 512 * 1024);

  k_prep<<<4608, 256, 0, stream>>>(x, xb, scores, Vw, Vt, Kw, Qw, G);
  k_symm<<<dim3(64, NS), 256, 0, stream>>>(G, Ut);
  k_scores<<<4096, 256, 0, stream>>>(xb, Ut, scores);
  k_weights<<<NB / 256, 256, 0, stream>>>(scores, wts);
  k_scale<<<2048, 256, 0, stream>>>(xb, wts, y);
  k_out<<<1024, 256, 0, stream>>>(xb, Vt, y);
}

// Round 8
// 364.277 us; speedup vs baseline: 1.7996x; 1.0973x over previous
//
#include <hip/hip_runtime.h>
#include <hip/hip_bf16.h>
#include <math.h>

// ---------------------------------------------------------------------------
// AttentionBlock: y[b,e] = sum_s w[b,s] * (x_bs @ V_s),
//   w = scores / ||scores||_2,  scores[b,s] = x_bs^T (Q_s K_s^T) x_bs
// Round 8 (R7 bugfix): k_out's B-staging violated the global_load_lds
// contract -- LDS dest is wave-uniform base + LANE*16, so the chunk base
// must encode the wave id. Rebuilt k_out as 64x256 tile (grid mt*2nt*8kg),
// 40KB LDS, per-wave B quarters, weight folded into reg-staged A.
// ---------------------------------------------------------------------------

typedef __attribute__((ext_vector_type(8))) short s8v;   // 8 x bf16 bits
typedef __attribute__((ext_vector_type(4))) float f4v;   // 4 x f32

#define MFMA_BF16(a, b, c) __builtin_amdgcn_mfma_f32_16x16x32_bf16((a), (b), (c), 0, 0, 0)

constexpr int NB = 4096;     // batch
constexpr int NS = 32;       // segments
constexpr int ND = 512;      // d per segment
constexpr int NE = 512;      // e (output dim)
constexpr int SD = NS * ND;  // 16384

__device__ __forceinline__ short f2bf(float f) {
  union { float f; unsigned u; } v; v.f = f;
  unsigned r = v.u + 0x7fffu + ((v.u >> 16) & 1u);  // RNE
  return (short)(r >> 16);
}
__device__ __forceinline__ float bf2f(short h) {
  union { unsigned u; float f; } v; v.u = ((unsigned)(unsigned short)h) << 16;
  return v.f;
}
__device__ __forceinline__ s8v cvt8(const float* p) {
  s8v r;
#pragma unroll
  for (int i = 0; i < 8; ++i) r[i] = f2bf(p[i]);
  return r;
}

// global -> LDS direct (16B per lane). LDS base must be wave-uniform;
// hardware writes base + lane*16 for the wave's 64 lanes.
__device__ __forceinline__ void gload16(const void* g, void* l) {
  __builtin_amdgcn_global_load_lds(
      (const __attribute__((address_space(1))) unsigned int*)g,
      (__attribute__((address_space(3))) unsigned int*)l, 16, 0, 0);
}

// ---------------------------------------------------------------------------
// K_prep: fused  [0,2048) castx + zero-scores | [2048,4096) transposeV |
//                [4096,4608) gram
// ---------------------------------------------------------------------------
__global__ __launch_bounds__(256) void k_prep(const float* __restrict__ x,
                                              short* __restrict__ xb,
                                              float* __restrict__ scores,
                                              const float* __restrict__ V,
                                              short* __restrict__ Vt,
                                              const float* __restrict__ Kw,
                                              const float* __restrict__ Qw,
                                              short* __restrict__ G) {
  __shared__ __align__(16) char smem[36864];
  int bid = blockIdx.x;
  int tid = threadIdx.x;

  if (bid < 2048) {
    // ---- castx: x f32 -> xb bf16, plus zero scores ----
    size_t gtid = (size_t)bid * 256 + tid;
    if (gtid < (size_t)NB * NS / 4) {
      f4v z = (f4v)0.0f;
      *(f4v*)(scores + gtid * 4) = z;
    }
    size_t i = gtid * 8;
    size_t stride = (size_t)2048 * 256 * 8;
    size_t total = (size_t)NB * SD;
    for (; i < total; i += stride) {
      f4v a = *(const f4v*)(x + i);
      f4v b = *(const f4v*)(x + i + 4);
      s8v o;
#pragma unroll
      for (int u = 0; u < 4; ++u) { o[u] = f2bf(a[u]); o[4 + u] = f2bf(b[u]); }
      *(s8v*)(xb + i) = o;
    }
  } else if (bid < 4096) {
    // ---- transposeV: V [SD,NE] f32 -> Vt [NE,SD] bf16 ----
    float (*t)[65] = (float(*)[65])smem;
    int t2 = bid - 2048;
    int k0 = (t2 & 255) * 64;
    int e0 = (t2 >> 8) * 64;
#pragma unroll
    for (int i = 0; i < 16; ++i) {
      int idx = tid + 256 * i;
      int r = idx >> 6, c = idx & 63;
      t[r][c] = V[(size_t)(k0 + r) * NE + e0 + c];
    }
    __syncthreads();
#pragma unroll
    for (int i = 0; i < 16; ++i) {
      int idx = tid + 256 * i;
      int e = idx >> 6, k = idx & 63;
      Vt[(size_t)(e0 + e) * SD + k0 + k] = f2bf(t[k][e]);
    }
  } else {
    // ---- gram: G_s[i][j] = sum_e K_s[i,e] * Q_s[j,e], 128x128 tile ----
    int t3 = bid - 4096;
    int s = t3 >> 4;
    int tm = (t3 >> 2) & 3, tn = t3 & 3;
    const float* A = Kw + (size_t)s * ND * NE + (size_t)tm * 128 * NE;
    const float* B = Qw + (size_t)s * ND * NE + (size_t)tn * 128 * NE;
    short* Gs = G + (size_t)s * ND * ND;

    s8v (*lsA)[9] = (s8v(*)[9])smem;
    s8v (*lsB)[9] = (s8v(*)[9])(smem + 18432);

    int lane = tid & 63, wid = tid >> 6;
    int wr = wid >> 1, wc = wid & 1;
    int lhi = lane >> 4, llo = lane & 15;

    float ra[4][8], rb[4][8];
    f4v acc[4][4];
#pragma unroll
    for (int i = 0; i < 4; ++i)
#pragma unroll
      for (int j = 0; j < 4; ++j) acc[i][j] = (f4v)0.0f;

    auto loadRegs = [&](int k0) {
#pragma unroll
      for (int i = 0; i < 4; ++i) {
        int c = tid + 256 * i; int row = c >> 3, k8 = c & 7;
        const float* p = A + (size_t)row * NE + k0 + k8 * 8;
        *(f4v*)&ra[i][0] = *(const f4v*)p;
        *(f4v*)&ra[i][4] = *(const f4v*)(p + 4);
        const float* q = B + (size_t)row * NE + k0 + k8 * 8;
        *(f4v*)&rb[i][0] = *(const f4v*)q;
        *(f4v*)&rb[i][4] = *(const f4v*)(q + 4);
      }
    };
    auto writeLds = [&]() {
#pragma unroll
      for (int i = 0; i < 4; ++i) {
        int c = tid + 256 * i; int row = c >> 3, k8 = c & 7;
        lsA[row][k8] = cvt8(ra[i]);
        lsB[row][k8] = cvt8(rb[i]);
      }
    };

    loadRegs(0);
    writeLds();
    for (int kt = 0; kt < 8; ++kt) {
      __syncthreads();
      if (kt + 1 < 8) loadRegs((kt + 1) * 64);
#pragma unroll
      for (int kk = 0; kk < 2; ++kk) {
        s8v af[4], bq[4];
#pragma unroll
        for (int i = 0; i < 4; ++i) af[i] = lsA[wr * 64 + i * 16 + llo][kk * 4 + lhi];
#pragma unroll
        for (int j = 0; j < 4; ++j) bq[j] = lsB[wc * 64 + j * 16 + llo][kk * 4 + lhi];
#pragma unroll
        for (int i = 0; i < 4; ++i)
#pragma unroll
          for (int j = 0; j < 4; ++j) acc[i][j] = MFMA_BF16(af[i], bq[j], acc[i][j]);
      }
      __syncthreads();
      if (kt + 1 < 8) writeLds();
    }

#pragma unroll
    for (int i = 0; i < 4; ++i)
#pragma unroll
      for (int r = 0; r < 4; ++r) {
        int row = tm * 128 + wr * 64 + i * 16 + lhi * 4 + r;
#pragma unroll
        for (int j = 0; j < 4; ++j) {
          int col = tn * 128 + wc * 64 + j * 16 + llo;
          Gs[(size_t)row * ND + col] = f2bf(acc[i][j][r]);
        }
      }
  }
}

// ---------------------------------------------------------------------------
// K_symm: U[a][b] = a<b ? G[a][b]+G[b][a] : (a==b ? G[a][a] : 0)
// ---------------------------------------------------------------------------
__global__ __launch_bounds__(256) void k_symm(const short* __restrict__ G,
                                              short* __restrict__ U) {
  int s = blockIdx.y;
  int kt = blockIdx.x >> 3, nt = blockIdx.x & 7;
  const short* Gs = G + (size_t)s * ND * ND;
  short* Us = U + (size_t)s * ND * ND;
  int k0 = kt * 64, n0 = nt * 64;
  int tid = threadIdx.x;
  int r = tid >> 2, cb = (tid & 3) * 16;

  if (kt > nt) {  // strictly below diagonal: zero
    s8v z = (s8v)(short)0;
    *(s8v*)&Us[(size_t)(k0 + r) * ND + n0 + cb] = z;
    *(s8v*)&Us[(size_t)(k0 + r) * ND + n0 + cb + 8] = z;
    return;
  }

  // tt[j][i] = G[n0+j][k0+i]
  __shared__ float tt[64][65];
  {
    const short* src = &Gs[(size_t)(n0 + r) * ND + k0 + cb];
    s8v a = *(const s8v*)src;
    s8v b = *(const s8v*)(src + 8);
#pragma unroll
    for (int u = 0; u < 8; ++u) { tt[r][cb + u] = bf2f(a[u]); tt[r][cb + 8 + u] = bf2f(b[u]); }
  }
  __syncthreads();
  {
    const short* src = &Gs[(size_t)(k0 + r) * ND + n0 + cb];
    s8v a = *(const s8v*)src;
    s8v b = *(const s8v*)(src + 8);
    s8v oa, ob;
#pragma unroll
    for (int u = 0; u < 8; ++u) {
      int k = k0 + r;
      int n1 = n0 + cb + u, n2 = n0 + cb + 8 + u;
      float g1 = bf2f(a[u]), g2 = bf2f(b[u]);
      float v1 = (k < n1) ? (g1 + tt[cb + u][r]) : ((k == n1) ? g1 : 0.f);
      float v2 = (k < n2) ? (g2 + tt[cb + 8 + u][r]) : ((k == n2) ? g2 : 0.f);
      oa[u] = f2bf(v1); ob[u] = f2bf(v2);
    }
    short* dst = &Us[(size_t)(k0 + r) * ND + n0 + cb];
    *(s8v*)dst = oa;
    *(s8v*)(dst + 8) = ob;
  }
}

// ---------------------------------------------------------------------------
// K3: T = Xb_s @ W (W[k][n] = U[n][k], nonzero k >= n),
//     scores[b,s] += sum_n Xb_s[b,n]*T[b,n]; K-loop kt in [2*nt, 8)
// ---------------------------------------------------------------------------
__global__ __launch_bounds__(256, 4) void k_scores(const short* __restrict__ xb,
                                                   const short* __restrict__ U,
                                                   float* __restrict__ scores) {
  int t = blockIdx.x;
  int swz = (t & 7) * 512 + (t >> 3);     // bijective, 4096 % 8 == 0
  int s = swz >> 7;
  int mt = (swz >> 2) & 31;
  int nt = swz & 3;
  int b0 = mt * 128, n0 = nt * 128;
  const short* Asrc = xb + (size_t)b0 * SD + s * ND;              // LD = SD
  const short* Bt = U + (size_t)s * ND * ND + (size_t)n0 * ND;    // rows = n

  __shared__ __align__(16) short lsA[128 * 64];
  __shared__ __align__(16) short lsB[128 * 64];

  int tid = threadIdx.x;
  int lane = tid & 63, wid = tid >> 6;
  int wr = wid >> 1, wc = wid & 1;
  int lhi = lane >> 4, llo = lane & 15;
  int lrow = lane >> 3, lcol = (lane & 7) * 8;

  f4v acc[4][4];
#pragma unroll
  for (int i = 0; i < 4; ++i)
#pragma unroll
    for (int j = 0; j < 4; ++j) acc[i][j] = (f4v)0.0f;

  for (int kt = 2 * nt; kt < 8; ++kt) {
    int k0 = kt * 64;
#pragma unroll
    for (int c = 0; c < 4; ++c) {
      int chunk = wid * 4 + c;
      int row = chunk * 8 + lrow;
      gload16(Asrc + (size_t)row * SD + k0 + lcol, (char*)lsA + chunk * 1024);
      gload16(Bt + (size_t)row * ND + k0 + lcol, (char*)lsB + chunk * 1024);
    }
    __syncthreads();
    const s8v* fA = (const s8v*)lsA;
    const s8v* fB = (const s8v*)lsB;
#pragma unroll
    for (int kk = 0; kk < 2; ++kk) {
      s8v af[4], bq[4];
#pragma unroll
      for (int i = 0; i < 4; ++i) af[i] = fA[(wr * 64 + i * 16 + llo) * 8 + kk * 4 + lhi];
#pragma unroll
      for (int j = 0; j < 4; ++j) bq[j] = fB[(wc * 64 + j * 16 + llo) * 8 + kk * 4 + lhi];
#pragma unroll
      for (int i = 0; i < 4; ++i)
#pragma unroll
        for (int j = 0; j < 4; ++j) acc[i][j] = MFMA_BF16(af[i], bq[j], acc[i][j]);
    }
    __syncthreads();
  }

#pragma unroll
  for (int i = 0; i < 4; ++i)
#pragma unroll
    for (int r = 0; r < 4; ++r) {
      int rowl = wr * 64 + i * 16 + lhi * 4 + r;
      int b = b0 + rowl;
      const short* xr = xb + (size_t)b * SD + s * ND + n0 + wc * 64;
      float v = 0.f;
#pragma unroll
      for (int j = 0; j < 4; ++j) v += bf2f(xr[j * 16 + llo]) * acc[i][j][r];
      v += __shfl_xor(v, 1);
      v += __shfl_xor(v, 2);
      v += __shfl_xor(v, 4);
      v += __shfl_xor(v, 8);
      if (llo == 0) atomicAdd(&scores[b * NS + s], v);
    }
}

// ---------------------------------------------------------------------------
// K4: weights = scores / ||scores||_2 + zero y (grid 2048)
// ---------------------------------------------------------------------------
__global__ __launch_bounds__(256) void k_weights(const float* __restrict__ scores,
                                                 float* __restrict__ w,
                                                 float* __restrict__ y) {
  int gtid = blockIdx.x * 256 + threadIdx.x;   // 524288 threads
  f4v z = (f4v)0.0f;
  *(f4v*)(y + (size_t)gtid * 4) = z;           // 2M floats = NB*NE
  if (gtid < NB) {
    float sq = 0.f, sc[NS];
#pragma unroll
    for (int s = 0; s < NS; ++s) { sc[s] = scores[gtid * NS + s]; sq += sc[s] * sc[s]; }
    float inv = 1.0f / sqrtf(sq);
#pragma unroll
    for (int s = 0; s < NS; ++s) w[gtid * NS + s] = sc[s] * inv;
  }
}

// ---------------------------------------------------------------------------
// K5: y += (w (.) xb) @ Vt^T   64x256 tile, BK=64, split-K 8 (kg = XCD)
//     grid 1024 = ((mt*2)+nt)*8 + kg. A reg-staged with weight; B per-wave
//     global_load_lds quarters (chunk base encodes wave id!).
// ---------------------------------------------------------------------------
__global__ __launch_bounds__(256, 3) void k_out(const short* __restrict__ xb,
                                                const float* __restrict__ wts,
                                                const short* __restrict__ Vt,
                                                float* __restrict__ y) {
  int t = blockIdx.x;
  int kg = t & 7;                // fastest -> XCD id
  int nt = (t >> 3) & 1;
  int mt = t >> 4;
  int b0 = mt * 64, n0 = nt * 256;
  const short* Asrc = xb + (size_t)b0 * SD + kg * 2048;
  const short* Bsrc = Vt + (size_t)n0 * SD + kg * 2048;   // 256 e-rows, LD = SD

  __shared__ __align__(16) short lsA[64 * 64];    // 8 KB
  __shared__ __align__(16) short lsB[256 * 64];   // 32 KB

  int tid = threadIdx.x;
  int lane = tid & 63, wid = tid >> 6;            // 4 waves: 1M x 4N
  int lhi = lane >> 4, llo = lane & 15;

  int arow0 = tid >> 3;            // 0..31
  int arow1 = 32 + (tid >> 3);     // 32..63
  int acb = (tid & 7) * 8;         // col offset (elements)

  f4v acc[4][4];
#pragma unroll
  for (int i = 0; i < 4; ++i)
#pragma unroll
    for (int j = 0; j < 4; ++j) acc[i][j] = (f4v)0.0f;

  for (int sl = 0; sl < 4; ++sl) {
    int s = kg * 4 + sl;
    float w0 = wts[(b0 + arow0) * NS + s];
    float w1 = wts[(b0 + arow1) * NS + s];
#pragma unroll 1
    for (int k8 = 0; k8 < 8; ++k8) {
      int k0 = sl * 512 + k8 * 64;
      // B: each wave stages its own quarter (rows wid*64 .. wid*64+63)
#pragma unroll
      for (int c = 0; c < 8; ++c) {
        int chunk = wid * 8 + c;           // 0..31 -> rows chunk*8..+7
        int idx = chunk * 64 + lane;       // row = idx>>3, colgrp = idx&7
        gload16(Bsrc + (size_t)(idx >> 3) * SD + k0 + (idx & 7) * 8,
                (char*)lsB + chunk * 1024);
      }
      // A: reg-stage 2 x 16B with weight applied
      s8v a0 = *(const s8v*)(Asrc + (size_t)arow0 * SD + k0 + acb);
      s8v a1 = *(const s8v*)(Asrc + (size_t)arow1 * SD + k0 + acb);
      s8v o0, o1;
#pragma unroll
      for (int u = 0; u < 8; ++u) {
        o0[u] = f2bf(bf2f(a0[u]) * w0);
        o1[u] = f2bf(bf2f(a1[u]) * w1);
      }
      *(s8v*)((char*)lsA + tid * 16) = o0;         // row arow0
      *(s8v*)((char*)lsA + 4096 + tid * 16) = o1;  // row arow1
      __syncthreads();   // drains vmcnt (B) + lgkm (A writes)
      const s8v* fA = (const s8v*)lsA;
      const s8v* fB = (const s8v*)lsB;
#pragma unroll
      for (int kk = 0; kk < 2; ++kk) {
        s8v af[4], bq[4];
#pragma unroll
        for (int i = 0; i < 4; ++i) af[i] = fA[(i * 16 + llo) * 8 + kk * 4 + lhi];
#pragma unroll
        for (int j = 0; j < 4; ++j) bq[j] = fB[(wid * 64 + j * 16 + llo) * 8 + kk * 4 + lhi];
#pragma unroll
        for (int i = 0; i < 4; ++i)
#pragma unroll
          for (int j = 0; j < 4; ++j) acc[i][j] = MFMA_BF16(af[i], bq[j], acc[i][j]);
      }
      __syncthreads();
    }
  }

#pragma unroll
  for (int i = 0; i < 4; ++i)
#pragma unroll
    for (int r = 0; r < 4; ++r) {
      int row = b0 + i * 16 + lhi * 4 + r;
#pragma unroll
      for (int j = 0; j < 4; ++j) {
        int col = n0 + wid * 64 + j * 16 + llo;
        atomicAdd(&y[(size_t)row * NE + col], acc[i][j][r]);
      }
    }
}

// ---------------------------------------------------------------------------
extern "C" void kernel_launch(void* const* d_in, const int* in_sizes, int n_in,
                              void* d_out, int out_size, void* d_ws, size_t ws_size,
                              hipStream_t stream) {
  const float* x  = (const float*)d_in[0];
  const float* Qw = (const float*)d_in[1];
  const float* Kw = (const float*)d_in[2];
  const float* Vw = (const float*)d_in[3];
  float* y = (float*)d_out;

  char* ws = (char*)d_ws;
  short* xb     = (short*)ws;                                    // 128 MiB
  short* G      = (short*)(ws + (size_t)128 * 1024 * 1024);      // 16 MiB
  short* Vt     = (short*)(ws + (size_t)144 * 1024 * 1024);      // 16 MiB
  short* Ut     = (short*)(ws + (size_t)160 * 1024 * 1024);      // 16 MiB
  float* scores = (float*)(ws + (size_t)176 * 1024 * 1024);      // 512 KiB
  float* wts    = (float*)(ws + (size_t)176 * 1024 * 1024 + 512 * 1024);

  k_prep<<<4608, 256, 0, stream>>>(x, xb, scores, Vw, Vt, Kw, Qw, G);
  k_symm<<<dim3(64, NS), 256, 0, stream>>>(G, Ut);
  k_scores<<<4096, 256, 0, stream>>>(xb, Ut, scores);
  k_weights<<<2048, 256, 0, stream>>>(scores, wts, y);
  k_out<<<1024, 256, 0, stream>>>(xb, wts, Vt, y);
}